// Round 7
// baseline (80.064 us; speedup 1.0000x reference)
//
#include <hip/hip_runtime.h>
#include <hip/hip_bf16.h>

// Quantized int8 3x3 conv via implicit-im2col MFMA (mfma_i32_32x32x32_i8).
// out = 1e-4*dot + asumf[px] + bconst[co]
//
// Round-7 structure:
//   - block 128co x 128px (2 output rows), 512 thr = 8 waves (4 wr x 2 wc),
//     wave tile 32co x 64px (m1 x p2), 8 MFMA per tap per wave
//   - input slab staged ONCE, TRANSPOSED planes [ci-chunk(8)][px(224)][16B]
//     -> px-contiguous ds_read_b128, conflict-free; tap offset folds to imm
//   - weights L2->regs, named-var double buffer (wa/wb), 4 clustered loads/tap
//   - no barriers in 9-tap loop; 4 waves/SIMD (launch_bounds 512,4)

#define N_B   32
#define C_IN  128
#define H_IN  56
#define W_IN  56
#define C_OUT 256
#define H_OUT 54
#define W_OUT 54
#define K_TOT 1152
#define NPX   (N_B * H_OUT * W_OUT)   // 93312
#define PXROW (H_OUT * W_OUT)         // 2916

using i32x4  = __attribute__((ext_vector_type(4))) int;
using i32x16 = __attribute__((ext_vector_type(16))) int;

static __device__ __forceinline__ int dot4(int a, int b, int c) {
#if __has_builtin(__builtin_amdgcn_sdot4)
  return __builtin_amdgcn_sdot4(a, b, c, false);
#else
  signed char a0 = (signed char)a, a1 = (signed char)(a >> 8),
              a2 = (signed char)(a >> 16), a3 = (signed char)(a >> 24);
  signed char b0 = (signed char)b, b1 = (signed char)(b >> 8),
              b2 = (signed char)(b >> 16), b3 = (signed char)(b >> 24);
  return c + a0 * b0 + a1 * b1 + a2 * b2 + a3 * b3;
#endif
}

__device__ __forceinline__ void gload16(const void* g, void* l) {
  __builtin_amdgcn_global_load_lds(
      (const __attribute__((address_space(1))) void*)g,
      (__attribute__((address_space(3))) void*)l, 16, 0, 0);
}

// ---------------- weight repack: OIHW(int32) -> wq3[t][kk][h][co][16] i8, bconst
// ci = kk*32 + h*16 + b  ->  offset = t*32768 + kk*8192 + h*4096 + co*16 + b
__global__ void repack_w(const int* __restrict__ w, const float* __restrict__ bias,
                         signed char* __restrict__ wq3, float* __restrict__ bconst) {
  int co = blockIdx.x;    // 256
  int ci = threadIdx.x;   // 128
  const int* wrow = w + (size_t)co * K_TOT + (size_t)ci * 9;
  int s = 0;
  int kk = ci >> 5, h = (ci >> 4) & 1, b = ci & 15;
  size_t base = (size_t)kk * 8192 + h * 4096 + co * 16 + b;
#pragma unroll
  for (int t = 0; t < 9; ++t) {
    int v = wrow[t];
    s += v;
    wq3[(size_t)t * 32768 + base] = (signed char)v;
  }
  __shared__ int red[128];
  red[ci] = s;
  __syncthreads();
  for (int off = 64; off > 0; off >>= 1) {
    if (ci < off) red[ci] += red[ci + off];
    __syncthreads();
  }
  if (ci == 0) {
    int wsum = red[0];
    float r = rintf(bias[co] / 0.0001f);                 // round half-even
    r = fminf(fmaxf(r, -2147483648.0f), 2147483647.0f);  // clamp to i32 range
    bconst[co] = 1e-4f * (float)(-7 * wsum + 24192) + r * 0.0001f;
  }
}

// ---------------- input repack: NCHW(int32) -> NHWC int8, fused per-px channel sums
__global__ void repack_in(const int* __restrict__ in, signed char* __restrict__ ip,
                          int* __restrict__ rs) {
  __shared__ int t32[C_IN * W_IN];   // 28KB
  __shared__ int rsum[W_IN];
  int h = blockIdx.x, n = blockIdx.y;
  int tid = threadIdx.x;
  if (tid < W_IN) rsum[tid] = 0;

  int ci = tid >> 1, hf = tid & 1;
  const int* s = in + ((size_t)n * C_IN + ci) * (H_IN * W_IN) + h * W_IN + hf * 28;
  int* d = &t32[ci * W_IN + hf * 28];
#pragma unroll
  for (int k = 0; k < 7; ++k)
    *(int4*)(d + k * 4) = *(const int4*)(s + k * 4);
  __syncthreads();

  signed char* dst = ip + (((size_t)n * H_IN + h) * W_IN) * C_IN;
  for (int j = tid; j < 448; j += 256) {
    int w = j >> 3, c16 = j & 7;
    int b[4], srow = 0;
#pragma unroll
    for (int q = 0; q < 4; ++q) {
      int x0 = t32[(c16 * 16 + q * 4 + 0) * W_IN + w];
      int x1 = t32[(c16 * 16 + q * 4 + 1) * W_IN + w];
      int x2 = t32[(c16 * 16 + q * 4 + 2) * W_IN + w];
      int x3 = t32[(c16 * 16 + q * 4 + 3) * W_IN + w];
      b[q] = (x0 & 255) | ((x1 & 255) << 8) | ((x2 & 255) << 16) | ((x3 & 255) << 24);
      srow = dot4(b[q], 0x01010101, srow);
    }
    *(int4*)(dst + (size_t)j * 16) = *(int4*)b;
    atomicAdd(&rsum[w], srow);
  }
  __syncthreads();
  if (tid < W_IN) rs[((size_t)n * H_IN + h) * W_IN + tid] = rsum[tid];
}

// ---------------- per-output-pixel: asumf = -3e-4 * receptive-field sum
__global__ void asum_k(const int* __restrict__ rs, float* __restrict__ asumf) {
  int px = blockIdx.x * 256 + threadIdx.x;
  if (px >= NPX) return;
  int n = px / PXROW, rem = px - n * PXROW;
  int y = rem / W_OUT, x = rem - y * W_OUT;
  const int* rp = rs + ((size_t)n * H_IN + y) * W_IN + x;
  int s = 0;
#pragma unroll
  for (int kh = 0; kh < 3; ++kh)
    s += rp[kh * W_IN + 0] + rp[kh * W_IN + 1] + rp[kh * W_IN + 2];
  asumf[px] = -3e-4f * (float)s;
}

// ---------------- main MFMA conv
__launch_bounds__(512, 4)
__global__ void conv_mfma(const signed char* __restrict__ ip,
                          const signed char* __restrict__ wq3,
                          const float* __restrict__ asumf,
                          const float* __restrict__ bconst,
                          float* __restrict__ out) {
  __shared__ signed char lds[32768];   // 8 planes x [256 px pad] x 16B
  const int tid = threadIdx.x, w = tid >> 6, l = tid & 63;
  const int wr = w >> 1, wc = w & 1;
  const int bx = blockIdx.x;           // 54: ct = bx&1, rp = bx>>1
  const int ct = bx & 1;
  const int rp = bx >> 1;
  const int n  = blockIdx.y;
  const int y0 = rp * 2;

  // ---- stage slab TRANSPOSED: plane c (ci-chunk) holds [px][16B]
  // dest L = i*8192 + tid*16  ->  plane c = i*2 + (tid>>8), px = tid&255
  const signed char* slab = ip + ((size_t)(n * H_IN + y0) * W_IN) * C_IN;
  {
    const int px = tid & 255;
    const int ch = tid >> 8;
    if (px < 224) {
#pragma unroll
      for (int i = 0; i < 4; ++i)
        gload16(slab + (size_t)px * 128 + (i * 2 + ch) * 16,
                &lds[i * 8192 + tid * 16]);
    }
  }

  // ---- per-lane B pixel bases: pf covers px j = wc*64 + pf*32 + (l&31)
  int jv[2], psb[2];
#pragma unroll
  for (int pf = 0; pf < 2; ++pf) {
    int j = wc * 64 + pf * 32 + (l & 31);
    jv[pf] = j;
    int jc = j > 107 ? 107 : j;
    int dy = (jc >= 54) ? 1 : 0;
    psb[pf] = dy * 56 + (jc - dy * 54);
  }
  const int h = l >> 5;
  const int lb0 = h * 4096 + psb[0] * 16;
  const int lb1 = h * 4096 + psb[1] * 16;

  // ---- A source: co = ct*128 + wr*32 + (l&31), k-chunk h
  const signed char* awq = wq3 + (size_t)h * 4096 +
                           (size_t)(ct * 128 + wr * 32 + (l & 31)) * 16;

  i32x16 acc0, acc1;
#pragma unroll
  for (int r = 0; r < 16; ++r) { acc0[r] = 0; acc1[r] = 0; }

#define LDW(V, t)                                                            \
  V##0 = *(const i32x4*)(awq + (size_t)(t) * 32768);                         \
  V##1 = *(const i32x4*)(awq + (size_t)(t) * 32768 + 8192);                  \
  V##2 = *(const i32x4*)(awq + (size_t)(t) * 32768 + 16384);                 \
  V##3 = *(const i32x4*)(awq + (size_t)(t) * 32768 + 24576);

#define TAP(t, A)                                                            \
  {                                                                          \
    constexpr int d16 = (((t) / 3) * 56 + ((t) % 3)) * 16;                   \
    i32x4 b00 = *(const i32x4*)(&lds[lb0 + d16]);                            \
    i32x4 b01 = *(const i32x4*)(&lds[lb1 + d16]);                            \
    i32x4 b10 = *(const i32x4*)(&lds[lb0 + d16 + 8192]);                     \
    i32x4 b11 = *(const i32x4*)(&lds[lb1 + d16 + 8192]);                     \
    i32x4 b20 = *(const i32x4*)(&lds[lb0 + d16 + 16384]);                    \
    i32x4 b21 = *(const i32x4*)(&lds[lb1 + d16 + 16384]);                    \
    i32x4 b30 = *(const i32x4*)(&lds[lb0 + d16 + 24576]);                    \
    i32x4 b31 = *(const i32x4*)(&lds[lb1 + d16 + 24576]);                    \
    __builtin_amdgcn_s_setprio(1);                                           \
    acc0 = __builtin_amdgcn_mfma_i32_32x32x32_i8(A##0, b00, acc0, 0, 0, 0);  \
    acc1 = __builtin_amdgcn_mfma_i32_32x32x32_i8(A##0, b01, acc1, 0, 0, 0);  \
    acc0 = __builtin_amdgcn_mfma_i32_32x32x32_i8(A##1, b10, acc0, 0, 0, 0);  \
    acc1 = __builtin_amdgcn_mfma_i32_32x32x32_i8(A##1, b11, acc1, 0, 0, 0);  \
    acc0 = __builtin_amdgcn_mfma_i32_32x32x32_i8(A##2, b20, acc0, 0, 0, 0);  \
    acc1 = __builtin_amdgcn_mfma_i32_32x32x32_i8(A##2, b21, acc1, 0, 0, 0);  \
    acc0 = __builtin_amdgcn_mfma_i32_32x32x32_i8(A##3, b30, acc0, 0, 0, 0);  \
    acc1 = __builtin_amdgcn_mfma_i32_32x32x32_i8(A##3, b31, acc1, 0, 0, 0);  \
    __builtin_amdgcn_s_setprio(0);                                           \
  }

  i32x4 wa0, wa1, wa2, wa3, wb0, wb1, wb2, wb3;
  LDW(wa, 0);
  __syncthreads();   // slab staged — the ONLY barrier

  LDW(wb, 1); TAP(0, wa);
  LDW(wa, 2); TAP(1, wb);
  LDW(wb, 3); TAP(2, wa);
  LDW(wa, 4); TAP(3, wb);
  LDW(wb, 5); TAP(4, wa);
  LDW(wa, 6); TAP(5, wb);
  LDW(wb, 7); TAP(6, wa);
  LDW(wa, 8); TAP(7, wb);
  TAP(8, wa);
#undef LDW
#undef TAP

  // ---- epilogue: C 32x32: px col = l&31, co row = (r&3) + 8*(r>>2) + 4*h
  float* obase = out + ((size_t)(n * C_OUT + ct * 128)) * PXROW + y0 * W_OUT;
  const float* apx = asumf + (size_t)n * PXROW + y0 * W_OUT;
  const float asf0 = apx[jv[0]];                       // jv0 <= 95 always valid
  const float asf1 = (jv[1] < 108) ? apx[jv[1]] : 0.0f;
  const int rbase = 4 * h;
#pragma unroll
  for (int r = 0; r < 16; ++r) {
    int col = wr * 32 + (r & 3) + 8 * (r >> 2) + rbase;  // co within ctile
    float bc = bconst[ct * 128 + col];
    float* o = obase + (size_t)col * PXROW;
    o[jv[0]] = 1e-4f * (float)acc0[r] + asf0 + bc;
    if (jv[1] < 108)
      o[jv[1]] = 1e-4f * (float)acc1[r] + asf1 + bc;
  }
}

// ---------------- fallback (tiny ws): naive direct conv
__global__ void conv_naive(const int* __restrict__ in, const int* __restrict__ w,
                           const float* __restrict__ bias, float* __restrict__ out) {
  size_t idx = (size_t)blockIdx.x * 256 + threadIdx.x;
  size_t total = (size_t)N_B * C_OUT * H_OUT * W_OUT;
  if (idx >= total) return;
  int x = idx % W_OUT; size_t t = idx / W_OUT;
  int y = t % H_OUT; t /= H_OUT;
  int co = t % C_OUT; int n = (int)(t / C_OUT);
  int acc = 0;
  for (int ci = 0; ci < C_IN; ++ci) {
    const int* ib = in + (((size_t)n * C_IN + ci) * H_IN + y) * W_IN + x;
    const int* wb = w + (((size_t)co * C_IN + ci) * 3) * 3;
    for (int kh = 0; kh < 3; ++kh)
      for (int kw = 0; kw < 3; ++kw)
        acc += (ib[kh * W_IN + kw] - 7) * (wb[kh * 3 + kw] - 3);
  }
  float r = rintf(bias[co] / 0.0001f);
  r = fminf(fmaxf(r, -2147483648.0f), 2147483647.0f);
  out[idx] = (float)acc * (0.01f * 0.01f) + r * 0.0001f;
}

extern "C" void kernel_launch(void* const* d_in, const int* in_sizes, int n_in,
                              void* d_out, int out_size, void* d_ws, size_t ws_size,
                              hipStream_t stream) {
  const int*   in   = (const int*)d_in[0];
  const int*   w    = (const int*)d_in[1];
  const float* bias = (const float*)d_in[2];
  float*       out  = (float*)d_out;

  const size_t WQ_OFF = 0;                        // 294912
  const size_t IP_OFF = 294912;                   // 12845056
  const size_t RS_OFF = IP_OFF + 12845056;        // 401408
  const size_t AF_OFF = RS_OFF + 401408;          // 373248
  const size_t BC_OFF = AF_OFF + 373248;          // 1024
  const size_t NEED   = BC_OFF + 1024;

  if (ws_size >= NEED) {
    char* ws = (char*)d_ws;
    signed char* wq3  = (signed char*)(ws + WQ_OFF);
    signed char* ip   = (signed char*)(ws + IP_OFF);
    int*         rs   = (int*)(ws + RS_OFF);
    float*       af   = (float*)(ws + AF_OFF);
    float*       bc   = (float*)(ws + BC_OFF);

    repack_w<<<C_OUT, 128, 0, stream>>>(w, bias, wq3, bc);
    repack_in<<<dim3(H_IN, N_B), 256, 0, stream>>>(in, ip, rs);
    asum_k<<<(NPX + 255) / 256, 256, 0, stream>>>(rs, af);
    conv_mfma<<<dim3(54, N_B), 512, 0, stream>>>(ip, wq3, af, bc, out);
  } else {
    size_t total = (size_t)N_B * C_OUT * H_OUT * W_OUT;
    conv_naive<<<(total + 255) / 256, 256, 0, stream>>>(in, w, bias, out);
  }
}

// Round 8
// 71.032 us; speedup vs baseline: 1.1272x; 1.1272x over previous
//
#include <hip/hip_runtime.h>
#include <hip/hip_bf16.h>

// Quantized int8 3x3 conv via implicit-im2col MFMA (mfma_i32_32x32x32_i8).
// out = 1e-4*dot + asumf[px] + bconst[co]
//
// Round-8 structure:
//   - input pre-transposed to ip2[n][h][q(8)][w(64 pad)][16B]: slab staging is
//     DENSE global_load_lds (1KB contiguous per wave-instr); B ds_reads are
//     px-contiguous (16B stride, conflict-free), tap offsets compile-time
//   - weights L2->regs, named wa/wb double buffer PINNED with sched_barrier(0)
//   - chunked XCD swizzle (1728 = 8*216) so ct-pairs/row-neighbors share L2
//   - block 128co x 128px (2 out rows), 512 thr, 8 waves (4wr x 2wc),
//     wave tile 32co x 64px, 8 MFMA/tap, no barriers in 9-tap loop

#define N_B   32
#define C_IN  128
#define H_IN  56
#define W_IN  56
#define C_OUT 256
#define H_OUT 54
#define W_OUT 54
#define K_TOT 1152
#define NPX   (N_B * H_OUT * W_OUT)   // 93312
#define PXROW (H_OUT * W_OUT)         // 2916

using i32x4  = __attribute__((ext_vector_type(4))) int;
using i32x16 = __attribute__((ext_vector_type(16))) int;

static __device__ __forceinline__ int dot4(int a, int b, int c) {
#if __has_builtin(__builtin_amdgcn_sdot4)
  return __builtin_amdgcn_sdot4(a, b, c, false);
#else
  signed char a0 = (signed char)a, a1 = (signed char)(a >> 8),
              a2 = (signed char)(a >> 16), a3 = (signed char)(a >> 24);
  signed char b0 = (signed char)b, b1 = (signed char)(b >> 8),
              b2 = (signed char)(b >> 16), b3 = (signed char)(b >> 24);
  return c + a0 * b0 + a1 * b1 + a2 * b2 + a3 * b3;
#endif
}

__device__ __forceinline__ void gload16(const void* g, void* l) {
  __builtin_amdgcn_global_load_lds(
      (const __attribute__((address_space(1))) void*)g,
      (__attribute__((address_space(3))) void*)l, 16, 0, 0);
}

// ---------------- weight repack: OIHW(int32) -> wq3[t][kk][h][co][16] i8, bconst
// ci = kk*32 + h*16 + b  ->  offset = t*32768 + kk*8192 + h*4096 + co*16 + b
__global__ void repack_w(const int* __restrict__ w, const float* __restrict__ bias,
                         signed char* __restrict__ wq3, float* __restrict__ bconst) {
  int co = blockIdx.x;    // 256
  int ci = threadIdx.x;   // 128
  const int* wrow = w + (size_t)co * K_TOT + (size_t)ci * 9;
  int s = 0;
  int kk = ci >> 5, h = (ci >> 4) & 1, b = ci & 15;
  size_t base = (size_t)kk * 8192 + h * 4096 + co * 16 + b;
#pragma unroll
  for (int t = 0; t < 9; ++t) {
    int v = wrow[t];
    s += v;
    wq3[(size_t)t * 32768 + base] = (signed char)v;
  }
  __shared__ int red[128];
  red[ci] = s;
  __syncthreads();
  for (int off = 64; off > 0; off >>= 1) {
    if (ci < off) red[ci] += red[ci + off];
    __syncthreads();
  }
  if (ci == 0) {
    int wsum = red[0];
    float r = rintf(bias[co] / 0.0001f);                 // round half-even
    r = fminf(fmaxf(r, -2147483648.0f), 2147483647.0f);  // clamp to i32 range
    bconst[co] = 1e-4f * (float)(-7 * wsum + 24192) + r * 0.0001f;
  }
}

// ---------------- input repack: NCHW(int32) -> ip2[n][h][q8][w64][16B] i8 + rowsums
__global__ void repack_in(const int* __restrict__ in, signed char* __restrict__ ip2,
                          int* __restrict__ rs) {
  __shared__ int t32[C_IN * W_IN];   // 28KB
  __shared__ int rsum[W_IN];
  int h = blockIdx.x, n = blockIdx.y;
  int tid = threadIdx.x;             // 256
  if (tid < W_IN) rsum[tid] = 0;

  int ci = tid >> 1, hf = tid & 1;
  const int* s = in + ((size_t)n * C_IN + ci) * (H_IN * W_IN) + h * W_IN + hf * 28;
  int* d = &t32[ci * W_IN + hf * 28];
#pragma unroll
  for (int k = 0; k < 7; ++k)
    *(int4*)(d + k * 4) = *(const int4*)(s + k * 4);
  __syncthreads();

  signed char* dst = ip2 + ((size_t)n * H_IN + h) * 8192;
#pragma unroll
  for (int jj = 0; jj < 2; ++jj) {
    int j = jj * 256 + tid;          // 0..511: q = j>>6, w = j&63
    int q = j >> 6, w = j & 63;
    if (w < W_IN) {
      int b[4], srow = 0;
#pragma unroll
      for (int qq = 0; qq < 4; ++qq) {
        int x0 = t32[(q * 16 + qq * 4 + 0) * W_IN + w];
        int x1 = t32[(q * 16 + qq * 4 + 1) * W_IN + w];
        int x2 = t32[(q * 16 + qq * 4 + 2) * W_IN + w];
        int x3 = t32[(q * 16 + qq * 4 + 3) * W_IN + w];
        b[qq] = (x0 & 255) | ((x1 & 255) << 8) | ((x2 & 255) << 16) | ((x3 & 255) << 24);
        srow = dot4(b[qq], 0x01010101, srow);
      }
      *(int4*)(dst + (size_t)q * 1024 + w * 16) = *(int4*)b;
      atomicAdd(&rsum[w], srow);
    }
  }
  __syncthreads();
  if (tid < W_IN) rs[((size_t)n * H_IN + h) * W_IN + tid] = rsum[tid];
}

// ---------------- per-output-pixel: asumf = -3e-4 * receptive-field sum
__global__ void asum_k(const int* __restrict__ rs, float* __restrict__ asumf) {
  int px = blockIdx.x * 256 + threadIdx.x;
  if (px >= NPX) return;
  int n = px / PXROW, rem = px - n * PXROW;
  int y = rem / W_OUT, x = rem - y * W_OUT;
  const int* rp = rs + ((size_t)n * H_IN + y) * W_IN + x;
  int s = 0;
#pragma unroll
  for (int kh = 0; kh < 3; ++kh)
    s += rp[kh * W_IN + 0] + rp[kh * W_IN + 1] + rp[kh * W_IN + 2];
  asumf[px] = -3e-4f * (float)s;
}

// ---------------- main MFMA conv
__launch_bounds__(512, 4)
__global__ void conv_mfma(const signed char* __restrict__ ip2,
                          const signed char* __restrict__ wq3,
                          const float* __restrict__ asumf,
                          const float* __restrict__ bconst,
                          float* __restrict__ out) {
  __shared__ signed char lds[32768];   // [q(8)][r(4)][w(64)][16B]
  const int tid = threadIdx.x, w = tid >> 6, l = tid & 63;
  const int wr = w >> 1, wc = w & 1;

  // chunked XCD swizzle: 1728 blocks = 8 xcd * 216
  const int b0 = blockIdx.x;
  const int wg = (b0 & 7) * 216 + (b0 >> 3);
  const int n  = wg / 54;
  const int bx = wg - n * 54;
  const int ct = bx & 1;
  const int rp = bx >> 1;
  const int y0 = rp * 2;

  // ---- stage slab DENSE: instr i covers q = {2i + tid>>8}, r = (tid>>6)&3
  const signed char* ipn = ip2 + ((size_t)n * H_IN + y0) * 8192;
  {
    const int q = tid >> 8;            // 0/1 per half-block
    const int r = (tid >> 6) & 3;
    const int off = (tid & 63) * 16;
    const signed char* src = ipn + (size_t)r * 8192 + q * 1024 + off;
#pragma unroll
    for (int i = 0; i < 4; ++i)
      gload16(src + (size_t)i * 2048, &lds[i * 8192 + tid * 16]);
  }

  // ---- per-lane B pixel bases: pf covers px j = wc*64 + pf*32 + (l&31)
  int jv[2], lb[2];
  const int h = l >> 5;
#pragma unroll
  for (int pf = 0; pf < 2; ++pf) {
    int j = wc * 64 + pf * 32 + (l & 31);
    jv[pf] = j;
    int jc = j > 107 ? 107 : j;
    int dy = (jc >= 54) ? 1 : 0;
    int x  = jc - dy * 54;
    lb[pf] = h * 4096 + dy * 1024 + x * 16;   // + kk*8192 + kh*1024 + kw*16
  }

  // ---- A source: co = ct*128 + wr*32 + (l&31), k-chunk h
  const signed char* awq = wq3 + (size_t)h * 4096 +
                           (size_t)(ct * 128 + wr * 32 + (l & 31)) * 16;

  i32x16 acc0, acc1;
#pragma unroll
  for (int r = 0; r < 16; ++r) { acc0[r] = 0; acc1[r] = 0; }

#define LDW(V, t)                                                            \
  V##0 = *(const i32x4*)(awq + (size_t)(t) * 32768);                         \
  V##1 = *(const i32x4*)(awq + (size_t)(t) * 32768 + 8192);                  \
  V##2 = *(const i32x4*)(awq + (size_t)(t) * 32768 + 16384);                 \
  V##3 = *(const i32x4*)(awq + (size_t)(t) * 32768 + 24576);

#define SB() __builtin_amdgcn_sched_barrier(0)

#define TAP(t, A)                                                            \
  {                                                                          \
    constexpr int d = ((t) / 3) * 1024 + ((t) % 3) * 16;                     \
    i32x4 b00 = *(const i32x4*)(&lds[lb[0] + d]);                            \
    i32x4 b01 = *(const i32x4*)(&lds[lb[1] + d]);                            \
    i32x4 b10 = *(const i32x4*)(&lds[lb[0] + d + 8192]);                     \
    i32x4 b11 = *(const i32x4*)(&lds[lb[1] + d + 8192]);                     \
    i32x4 b20 = *(const i32x4*)(&lds[lb[0] + d + 16384]);                    \
    i32x4 b21 = *(const i32x4*)(&lds[lb[1] + d + 16384]);                    \
    i32x4 b30 = *(const i32x4*)(&lds[lb[0] + d + 24576]);                    \
    i32x4 b31 = *(const i32x4*)(&lds[lb[1] + d + 24576]);                    \
    __builtin_amdgcn_s_setprio(1);                                           \
    acc0 = __builtin_amdgcn_mfma_i32_32x32x32_i8(A##0, b00, acc0, 0, 0, 0);  \
    acc1 = __builtin_amdgcn_mfma_i32_32x32x32_i8(A##0, b01, acc1, 0, 0, 0);  \
    acc0 = __builtin_amdgcn_mfma_i32_32x32x32_i8(A##1, b10, acc0, 0, 0, 0);  \
    acc1 = __builtin_amdgcn_mfma_i32_32x32x32_i8(A##1, b11, acc1, 0, 0, 0);  \
    acc0 = __builtin_amdgcn_mfma_i32_32x32x32_i8(A##2, b20, acc0, 0, 0, 0);  \
    acc1 = __builtin_amdgcn_mfma_i32_32x32x32_i8(A##2, b21, acc1, 0, 0, 0);  \
    acc0 = __builtin_amdgcn_mfma_i32_32x32x32_i8(A##3, b30, acc0, 0, 0, 0);  \
    acc1 = __builtin_amdgcn_mfma_i32_32x32x32_i8(A##3, b31, acc1, 0, 0, 0);  \
    __builtin_amdgcn_s_setprio(0);                                           \
  }

  i32x4 wa0, wa1, wa2, wa3, wb0, wb1, wb2, wb3;
  LDW(wa, 0);
  __syncthreads();   // slab staged — the ONLY barrier

  LDW(wb, 1); SB(); TAP(0, wa);
  LDW(wa, 2); SB(); TAP(1, wb);
  LDW(wb, 3); SB(); TAP(2, wa);
  LDW(wa, 4); SB(); TAP(3, wb);
  LDW(wb, 5); SB(); TAP(4, wa);
  LDW(wa, 6); SB(); TAP(5, wb);
  LDW(wb, 7); SB(); TAP(6, wa);
  LDW(wa, 8); SB(); TAP(7, wb);
  SB(); TAP(8, wa);
#undef LDW
#undef TAP
#undef SB

  // ---- epilogue: C 32x32: px col = l&31, co row = (r&3) + 8*(r>>2) + 4*h
  float* obase = out + ((size_t)(n * C_OUT + ct * 128)) * PXROW + y0 * W_OUT;
  const float* apx = asumf + (size_t)n * PXROW + y0 * W_OUT;
  const float asf0 = apx[jv[0]];                       // jv0 <= 95 always valid
  const float asf1 = (jv[1] < 108) ? apx[jv[1]] : 0.0f;
  const int rbase = 4 * h;
#pragma unroll
  for (int r = 0; r < 16; ++r) {
    int col = wr * 32 + (r & 3) + 8 * (r >> 2) + rbase;  // co within ctile
    float bc = bconst[ct * 128 + col];
    float* o = obase + (size_t)col * PXROW;
    o[jv[0]] = 1e-4f * (float)acc0[r] + asf0 + bc;
    if (jv[1] < 108)
      o[jv[1]] = 1e-4f * (float)acc1[r] + asf1 + bc;
  }
}

// ---------------- fallback (tiny ws): naive direct conv
__global__ void conv_naive(const int* __restrict__ in, const int* __restrict__ w,
                           const float* __restrict__ bias, float* __restrict__ out) {
  size_t idx = (size_t)blockIdx.x * 256 + threadIdx.x;
  size_t total = (size_t)N_B * C_OUT * H_OUT * W_OUT;
  if (idx >= total) return;
  int x = idx % W_OUT; size_t t = idx / W_OUT;
  int y = t % H_OUT; t /= H_OUT;
  int co = t % C_OUT; int n = (int)(t / C_OUT);
  int acc = 0;
  for (int ci = 0; ci < C_IN; ++ci) {
    const int* ib = in + (((size_t)n * C_IN + ci) * H_IN + y) * W_IN + x;
    const int* wb = w + (((size_t)co * C_IN + ci) * 3) * 3;
    for (int kh = 0; kh < 3; ++kh)
      for (int kw = 0; kw < 3; ++kw)
        acc += (ib[kh * W_IN + kw] - 7) * (wb[kh * 3 + kw] - 3);
  }
  float r = rintf(bias[co] / 0.0001f);
  r = fminf(fmaxf(r, -2147483648.0f), 2147483647.0f);
  out[idx] = (float)acc * (0.01f * 0.01f) + r * 0.0001f;
}

extern "C" void kernel_launch(void* const* d_in, const int* in_sizes, int n_in,
                              void* d_out, int out_size, void* d_ws, size_t ws_size,
                              hipStream_t stream) {
  const int*   in   = (const int*)d_in[0];
  const int*   w    = (const int*)d_in[1];
  const float* bias = (const float*)d_in[2];
  float*       out  = (float*)d_out;

  const size_t WQ_OFF = 0;                          // 294912
  const size_t IP_OFF = 294912;                     // 32*56*8192 = 14680064
  const size_t RS_OFF = IP_OFF + 14680064;          // 401408
  const size_t AF_OFF = RS_OFF + 401408;            // 373248
  const size_t BC_OFF = AF_OFF + 373248;            // 1024
  const size_t NEED   = BC_OFF + 1024;              // ~15.75 MB

  if (ws_size >= NEED) {
    char* ws = (char*)d_ws;
    signed char* wq3  = (signed char*)(ws + WQ_OFF);
    signed char* ip2  = (signed char*)(ws + IP_OFF);
    int*         rs   = (int*)(ws + RS_OFF);
    float*       af   = (float*)(ws + AF_OFF);
    float*       bc   = (float*)(ws + BC_OFF);

    repack_w<<<C_OUT, 128, 0, stream>>>(w, bias, wq3, bc);
    repack_in<<<dim3(H_IN, N_B), 256, 0, stream>>>(in, ip2, rs);
    asum_k<<<(NPX + 255) / 256, 256, 0, stream>>>(rs, af);
    conv_mfma<<<1728, 512, 0, stream>>>(ip2, wq3, af, bc, out);
  } else {
    size_t total = (size_t)N_B * C_OUT * H_OUT * W_OUT;
    conv_naive<<<(total + 255) / 256, 256, 0, stream>>>(in, w, bias, out);
  }
}

// Round 9
// 67.325 us; speedup vs baseline: 1.1892x; 1.0551x over previous
//
#include <hip/hip_runtime.h>
#include <hip/hip_bf16.h>

// Quantized int8 3x3 conv via implicit-im2col MFMA (mfma_i32_32x32x32_i8).
// out = 1e-4*dot + asumf[px] + bconst[co]
//
// Round-9 structure:
//   - block 128co x 128px (2 out rows), 256 thr = 4 waves, wave = 32co x 128px
//     (m1 x p4 x kk4 = 16 MFMA/tap) -> A fragments reused 4x: A L2 traffic
//     halves vs R8 (~250MB total = 7us), tap compute phase 2x longer so the
//     wa/wb register double-buffer hides L2 latency
//   - input slab ip2[n][h][q8][w64][16B] staged dense once, 32KB LDS only;
//     ~3 blocks/CU at different phases overlap L2/LDS/MFMA/store pipes
//   - weights L2->regs, named wa/wb dbuf pinned by sched_barrier(0)
//   - chunked XCD swizzle (1728 = 8*216); no barriers in 9-tap loop

#define N_B   32
#define C_IN  128
#define H_IN  56
#define W_IN  56
#define C_OUT 256
#define H_OUT 54
#define W_OUT 54
#define K_TOT 1152
#define NPX   (N_B * H_OUT * W_OUT)   // 93312
#define PXROW (H_OUT * W_OUT)         // 2916

using i32x4  = __attribute__((ext_vector_type(4))) int;
using i32x16 = __attribute__((ext_vector_type(16))) int;

static __device__ __forceinline__ int dot4(int a, int b, int c) {
#if __has_builtin(__builtin_amdgcn_sdot4)
  return __builtin_amdgcn_sdot4(a, b, c, false);
#else
  signed char a0 = (signed char)a, a1 = (signed char)(a >> 8),
              a2 = (signed char)(a >> 16), a3 = (signed char)(a >> 24);
  signed char b0 = (signed char)b, b1 = (signed char)(b >> 8),
              b2 = (signed char)(b >> 16), b3 = (signed char)(b >> 24);
  return c + a0 * b0 + a1 * b1 + a2 * b2 + a3 * b3;
#endif
}

__device__ __forceinline__ void gload16(const void* g, void* l) {
  __builtin_amdgcn_global_load_lds(
      (const __attribute__((address_space(1))) void*)g,
      (__attribute__((address_space(3))) void*)l, 16, 0, 0);
}

// ---------------- weight repack: OIHW(int32) -> wq3[t][kk][h][co][16] i8, bconst
// ci = kk*32 + h*16 + b  ->  offset = t*32768 + kk*8192 + h*4096 + co*16 + b
__global__ void repack_w(const int* __restrict__ w, const float* __restrict__ bias,
                         signed char* __restrict__ wq3, float* __restrict__ bconst) {
  int co = blockIdx.x;    // 256
  int ci = threadIdx.x;   // 128
  const int* wrow = w + (size_t)co * K_TOT + (size_t)ci * 9;
  int s = 0;
  int kk = ci >> 5, h = (ci >> 4) & 1, b = ci & 15;
  size_t base = (size_t)kk * 8192 + h * 4096 + co * 16 + b;
#pragma unroll
  for (int t = 0; t < 9; ++t) {
    int v = wrow[t];
    s += v;
    wq3[(size_t)t * 32768 + base] = (signed char)v;
  }
  __shared__ int red[128];
  red[ci] = s;
  __syncthreads();
  for (int off = 64; off > 0; off >>= 1) {
    if (ci < off) red[ci] += red[ci + off];
    __syncthreads();
  }
  if (ci == 0) {
    int wsum = red[0];
    float r = rintf(bias[co] / 0.0001f);                 // round half-even
    r = fminf(fmaxf(r, -2147483648.0f), 2147483647.0f);  // clamp to i32 range
    bconst[co] = 1e-4f * (float)(-7 * wsum + 24192) + r * 0.0001f;
  }
}

// ---------------- input repack: NCHW(int32) -> ip2[n][h][q8][w64][16B] i8 + rowsums
__global__ void repack_in(const int* __restrict__ in, signed char* __restrict__ ip2,
                          int* __restrict__ rs) {
  __shared__ int t32[C_IN * W_IN];   // 28KB
  __shared__ int rsum[W_IN];
  int h = blockIdx.x, n = blockIdx.y;
  int tid = threadIdx.x;             // 256
  if (tid < W_IN) rsum[tid] = 0;

  int ci = tid >> 1, hf = tid & 1;
  const int* s = in + ((size_t)n * C_IN + ci) * (H_IN * W_IN) + h * W_IN + hf * 28;
  int* d = &t32[ci * W_IN + hf * 28];
#pragma unroll
  for (int k = 0; k < 7; ++k)
    *(int4*)(d + k * 4) = *(const int4*)(s + k * 4);
  __syncthreads();

  signed char* dst = ip2 + ((size_t)n * H_IN + h) * 8192;
#pragma unroll
  for (int jj = 0; jj < 2; ++jj) {
    int j = jj * 256 + tid;          // 0..511: q = j>>6, w = j&63
    int q = j >> 6, w = j & 63;
    if (w < W_IN) {
      int b[4], srow = 0;
#pragma unroll
      for (int qq = 0; qq < 4; ++qq) {
        int x0 = t32[(q * 16 + qq * 4 + 0) * W_IN + w];
        int x1 = t32[(q * 16 + qq * 4 + 1) * W_IN + w];
        int x2 = t32[(q * 16 + qq * 4 + 2) * W_IN + w];
        int x3 = t32[(q * 16 + qq * 4 + 3) * W_IN + w];
        b[qq] = (x0 & 255) | ((x1 & 255) << 8) | ((x2 & 255) << 16) | ((x3 & 255) << 24);
        srow = dot4(b[qq], 0x01010101, srow);
      }
      *(int4*)(dst + (size_t)q * 1024 + w * 16) = *(int4*)b;
      atomicAdd(&rsum[w], srow);
    }
  }
  __syncthreads();
  if (tid < W_IN) rs[((size_t)n * H_IN + h) * W_IN + tid] = rsum[tid];
}

// ---------------- per-output-pixel: asumf = -3e-4 * receptive-field sum
__global__ void asum_k(const int* __restrict__ rs, float* __restrict__ asumf) {
  int px = blockIdx.x * 256 + threadIdx.x;
  if (px >= NPX) return;
  int n = px / PXROW, rem = px - n * PXROW;
  int y = rem / W_OUT, x = rem - y * W_OUT;
  const int* rp = rs + ((size_t)n * H_IN + y) * W_IN + x;
  int s = 0;
#pragma unroll
  for (int kh = 0; kh < 3; ++kh)
    s += rp[kh * W_IN + 0] + rp[kh * W_IN + 1] + rp[kh * W_IN + 2];
  asumf[px] = -3e-4f * (float)s;
}

// ---------------- main MFMA conv
__launch_bounds__(256, 4)
__global__ void conv_mfma(const signed char* __restrict__ ip2,
                          const signed char* __restrict__ wq3,
                          const float* __restrict__ asumf,
                          const float* __restrict__ bconst,
                          float* __restrict__ out) {
  __shared__ signed char lds[32768];   // [i(8)=kk*2+h][r(4)][w(64)][16B]
  const int tid = threadIdx.x, w = tid >> 6, l = tid & 63;

  // chunked XCD swizzle: 1728 blocks = 8 xcd * 216
  const int b0i = blockIdx.x;
  const int wg = (b0i & 7) * 216 + (b0i >> 3);
  const int n  = wg / 54;
  const int bx = wg - n * 54;
  const int ct = bx & 1;
  const int rp = bx >> 1;
  const int y0 = rp * 2;

  // ---- stage slab DENSE: instr i -> plane q=i; thread covers (r = tid>>6, w)
  const signed char* ipn = ip2 + ((size_t)n * H_IN + y0) * 8192;
  {
    const int r = tid >> 6;
    const int off = (tid & 63) * 16;
    const signed char* src = ipn + (size_t)r * 8192 + off;
#pragma unroll
    for (int i = 0; i < 8; ++i)
      gload16(src + (size_t)i * 1024, &lds[i * 4096 + tid * 16]);
  }

  // ---- per-lane B pixel bases: pf covers px j = pf*32 + (l&31)
  const int h = l >> 5;
  int lb[4];
#pragma unroll
  for (int pf = 0; pf < 4; ++pf) {
    int j = pf * 32 + (l & 31);
    int jc = j > 107 ? 107 : j;
    int dy = (jc >= 54) ? 1 : 0;
    int x  = jc - dy * 54;
    lb[pf] = h * 4096 + dy * 1024 + x * 16;   // + kk*8192 + kh*1024 + kw*16
  }

  // ---- A source: co = ct*128 + w*32 + (l&31), k-chunk h
  const signed char* awq = wq3 + (size_t)h * 4096 +
                           (size_t)(ct * 128 + w * 32 + (l & 31)) * 16;

  i32x16 acc0, acc1, acc2, acc3;
#pragma unroll
  for (int r = 0; r < 16; ++r) { acc0[r] = 0; acc1[r] = 0; acc2[r] = 0; acc3[r] = 0; }

#define LDW(V, t)                                                            \
  V##0 = *(const i32x4*)(awq + (size_t)(t) * 32768);                         \
  V##1 = *(const i32x4*)(awq + (size_t)(t) * 32768 + 8192);                  \
  V##2 = *(const i32x4*)(awq + (size_t)(t) * 32768 + 16384);                 \
  V##3 = *(const i32x4*)(awq + (size_t)(t) * 32768 + 24576);

#define SB() __builtin_amdgcn_sched_barrier(0)

#define KKSTEP(Ak, koff)                                                        \
  {                                                                             \
    i32x4 bq0 = *(const i32x4*)(&lds[lb[0] + d + (koff)]);                      \
    i32x4 bq1 = *(const i32x4*)(&lds[lb[1] + d + (koff)]);                      \
    i32x4 bq2 = *(const i32x4*)(&lds[lb[2] + d + (koff)]);                      \
    i32x4 bq3 = *(const i32x4*)(&lds[lb[3] + d + (koff)]);                      \
    __builtin_amdgcn_s_setprio(1);                                              \
    acc0 = __builtin_amdgcn_mfma_i32_32x32x32_i8(Ak, bq0, acc0, 0, 0, 0);       \
    acc1 = __builtin_amdgcn_mfma_i32_32x32x32_i8(Ak, bq1, acc1, 0, 0, 0);       \
    acc2 = __builtin_amdgcn_mfma_i32_32x32x32_i8(Ak, bq2, acc2, 0, 0, 0);       \
    acc3 = __builtin_amdgcn_mfma_i32_32x32x32_i8(Ak, bq3, acc3, 0, 0, 0);       \
    __builtin_amdgcn_s_setprio(0);                                              \
  }

#define TAP(t, A)                                                               \
  {                                                                             \
    const int d = ((t) / 3) * 1024 + ((t) % 3) * 16;                            \
    KKSTEP(A##0, 0)                                                             \
    KKSTEP(A##1, 8192)                                                          \
    KKSTEP(A##2, 16384)                                                         \
    KKSTEP(A##3, 24576)                                                         \
  }

  i32x4 wa0, wa1, wa2, wa3, wb0, wb1, wb2, wb3;
  LDW(wa, 0);
  __syncthreads();   // slab + wa staged — the ONLY barrier

  LDW(wb, 1); SB(); TAP(0, wa);
  LDW(wa, 2); SB(); TAP(1, wb);
  LDW(wb, 3); SB(); TAP(2, wa);
  LDW(wa, 4); SB(); TAP(3, wb);
  LDW(wb, 5); SB(); TAP(4, wa);
  LDW(wa, 6); SB(); TAP(5, wb);
  LDW(wb, 7); SB(); TAP(6, wa);
  LDW(wa, 8); SB(); TAP(7, wb);
  SB(); TAP(8, wa);
#undef LDW
#undef TAP
#undef KKSTEP
#undef SB

  // ---- epilogue: C 32x32: px col = l&31, co row = (r&3) + 8*(r>>2) + 4*h
  float* obase = out + ((size_t)(n * C_OUT + ct * 128)) * PXROW + y0 * W_OUT;
  const float* apx = asumf + (size_t)n * PXROW + y0 * W_OUT;
  const int j0 = l & 31;                     // jv[pf] = pf*32 + j0
  const float asf0 = apx[j0];
  const float asf1 = apx[32 + j0];
  const float asf2 = apx[64 + j0];
  const float asf3 = (96 + j0 < 108) ? apx[96 + j0] : 0.0f;
  const int rbase = 4 * h;
#pragma unroll
  for (int r = 0; r < 16; ++r) {
    int col = w * 32 + (r & 3) + 8 * (r >> 2) + rbase;   // co within ctile
    float bc = bconst[ct * 128 + col];
    float* o = obase + (size_t)col * PXROW;
    o[j0]      = 1e-4f * (float)acc0[r] + asf0 + bc;
    o[32 + j0] = 1e-4f * (float)acc1[r] + asf1 + bc;
    o[64 + j0] = 1e-4f * (float)acc2[r] + asf2 + bc;
    if (96 + j0 < 108)
      o[96 + j0] = 1e-4f * (float)acc3[r] + asf3 + bc;
  }
}

// ---------------- fallback (tiny ws): naive direct conv
__global__ void conv_naive(const int* __restrict__ in, const int* __restrict__ w,
                           const float* __restrict__ bias, float* __restrict__ out) {
  size_t idx = (size_t)blockIdx.x * 256 + threadIdx.x;
  size_t total = (size_t)N_B * C_OUT * H_OUT * W_OUT;
  if (idx >= total) return;
  int x = idx % W_OUT; size_t t = idx / W_OUT;
  int y = t % H_OUT; t /= H_OUT;
  int co = t % C_OUT; int n = (int)(t / C_OUT);
  int acc = 0;
  for (int ci = 0; ci < C_IN; ++ci) {
    const int* ib = in + (((size_t)n * C_IN + ci) * H_IN + y) * W_IN + x;
    const int* wb = w + (((size_t)co * C_IN + ci) * 3) * 3;
    for (int kh = 0; kh < 3; ++kh)
      for (int kw = 0; kw < 3; ++kw)
        acc += (ib[kh * W_IN + kw] - 7) * (wb[kh * 3 + kw] - 3);
  }
  float r = rintf(bias[co] / 0.0001f);
  r = fminf(fmaxf(r, -2147483648.0f), 2147483647.0f);
  out[idx] = (float)acc * (0.01f * 0.01f) + r * 0.0001f;
}

extern "C" void kernel_launch(void* const* d_in, const int* in_sizes, int n_in,
                              void* d_out, int out_size, void* d_ws, size_t ws_size,
                              hipStream_t stream) {
  const int*   in   = (const int*)d_in[0];
  const int*   w    = (const int*)d_in[1];
  const float* bias = (const float*)d_in[2];
  float*       out  = (float*)d_out;

  const size_t WQ_OFF = 0;                          // 294912
  const size_t IP_OFF = 294912;                     // 32*56*8192 = 14680064
  const size_t RS_OFF = IP_OFF + 14680064;          // 401408
  const size_t AF_OFF = RS_OFF + 401408;            // 373248
  const size_t BC_OFF = AF_OFF + 373248;            // 1024
  const size_t NEED   = BC_OFF + 1024;              // ~15.75 MB

  if (ws_size >= NEED) {
    char* ws = (char*)d_ws;
    signed char* wq3  = (signed char*)(ws + WQ_OFF);
    signed char* ip2  = (signed char*)(ws + IP_OFF);
    int*         rs   = (int*)(ws + RS_OFF);
    float*       af   = (float*)(ws + AF_OFF);
    float*       bc   = (float*)(ws + BC_OFF);

    repack_w<<<C_OUT, 128, 0, stream>>>(w, bias, wq3, bc);
    repack_in<<<dim3(H_IN, N_B), 256, 0, stream>>>(in, ip2, rs);
    asum_k<<<(NPX + 255) / 256, 256, 0, stream>>>(rs, af);
    conv_mfma<<<1728, 256, 0, stream>>>(ip2, wq3, af, bc, out);
  } else {
    size_t total = (size_t)N_B * C_OUT * H_OUT * W_OUT;
    conv_naive<<<(total + 255) / 256, 256, 0, stream>>>(in, w, bias, out);
  }
}

// Round 10
// 58.486 us; speedup vs baseline: 1.3689x; 1.1511x over previous
//
#include <hip/hip_runtime.h>
#include <hip/hip_bf16.h>

// Quantized int8 3x3 conv via implicit-im2col MFMA (mfma_i32_16x16x64_i8).
// out = 1e-4*dot + asumf[px] + bconst[co]
//
// Round-10 structure:
//   - 16x16x64 MFMA: wave tile 16co x 112px (m1 x p7) -> acc only 28 VGPR;
//     ~90 VGPR/wave -> launch_bounds(256,5): 5 blocks/CU (160KB LDS), 20 waves/CU
//   - block 64co x 112px (2 out rows), 4 waves; grid 3456 = 32n x 27rp x 4cq
//   - px tile 112 vs 128: 12.5% less padded MFMA work
//   - A: L2->regs, 4 regs/kstep, triple-buffered 2 ksteps ahead, SB-pinned
//   - B: 7 ds_read_b128/kstep (px-contiguous, conflict-free), 7 indep MFMAs
//   - XCD swizzle keeps the 4 co-quarters of one slab on the same XCD

#define N_B   32
#define C_IN  128
#define H_IN  56
#define W_IN  56
#define C_OUT 256
#define H_OUT 54
#define W_OUT 54
#define K_TOT 1152
#define NPX   (N_B * H_OUT * W_OUT)   // 93312
#define PXROW (H_OUT * W_OUT)         // 2916

using i32x4  = __attribute__((ext_vector_type(4))) int;

static __device__ __forceinline__ int dot4(int a, int b, int c) {
#if __has_builtin(__builtin_amdgcn_sdot4)
  return __builtin_amdgcn_sdot4(a, b, c, false);
#else
  signed char a0 = (signed char)a, a1 = (signed char)(a >> 8),
              a2 = (signed char)(a >> 16), a3 = (signed char)(a >> 24);
  signed char b0 = (signed char)b, b1 = (signed char)(b >> 8),
              b2 = (signed char)(b >> 16), b3 = (signed char)(b >> 24);
  return c + a0 * b0 + a1 * b1 + a2 * b2 + a3 * b3;
#endif
}

__device__ __forceinline__ void gload16(const void* g, void* l) {
  __builtin_amdgcn_global_load_lds(
      (const __attribute__((address_space(1))) void*)g,
      (__attribute__((address_space(3))) void*)l, 16, 0, 0);
}

// ---------------- weight repack: OIHW(int32) -> wq3[t][kk][h][co][16] i8, bconst
// ci = kk*32 + h*16 + b  ->  offset = t*32768 + kk*8192 + h*4096 + co*16 + b
// (for 16x16x64 fragments this collapses to ks*16384 + c16*4096 + co*16)
__global__ void repack_w(const int* __restrict__ w, const float* __restrict__ bias,
                         signed char* __restrict__ wq3, float* __restrict__ bconst) {
  int co = blockIdx.x;    // 256
  int ci = threadIdx.x;   // 128
  const int* wrow = w + (size_t)co * K_TOT + (size_t)ci * 9;
  int s = 0;
  int kk = ci >> 5, h = (ci >> 4) & 1, b = ci & 15;
  size_t base = (size_t)kk * 8192 + h * 4096 + co * 16 + b;
#pragma unroll
  for (int t = 0; t < 9; ++t) {
    int v = wrow[t];
    s += v;
    wq3[(size_t)t * 32768 + base] = (signed char)v;
  }
  __shared__ int red[128];
  red[ci] = s;
  __syncthreads();
  for (int off = 64; off > 0; off >>= 1) {
    if (ci < off) red[ci] += red[ci + off];
    __syncthreads();
  }
  if (ci == 0) {
    int wsum = red[0];
    float r = rintf(bias[co] / 0.0001f);                 // round half-even
    r = fminf(fmaxf(r, -2147483648.0f), 2147483647.0f);  // clamp to i32 range
    bconst[co] = 1e-4f * (float)(-7 * wsum + 24192) + r * 0.0001f;
  }
}

// ---------------- input repack: NCHW(int32) -> ip2[n][h][q8][w64][16B] i8 + rowsums
__global__ void repack_in(const int* __restrict__ in, signed char* __restrict__ ip2,
                          int* __restrict__ rs) {
  __shared__ int t32[C_IN * W_IN];   // 28KB
  __shared__ int rsum[W_IN];
  int h = blockIdx.x, n = blockIdx.y;
  int tid = threadIdx.x;             // 256
  if (tid < W_IN) rsum[tid] = 0;

  int ci = tid >> 1, hf = tid & 1;
  const int* s = in + ((size_t)n * C_IN + ci) * (H_IN * W_IN) + h * W_IN + hf * 28;
  int* d = &t32[ci * W_IN + hf * 28];
#pragma unroll
  for (int k = 0; k < 7; ++k)
    *(int4*)(d + k * 4) = *(const int4*)(s + k * 4);
  __syncthreads();

  signed char* dst = ip2 + ((size_t)n * H_IN + h) * 8192;
#pragma unroll
  for (int jj = 0; jj < 2; ++jj) {
    int j = jj * 256 + tid;          // 0..511: q = j>>6, w = j&63
    int q = j >> 6, w = j & 63;
    if (w < W_IN) {
      int b[4], srow = 0;
#pragma unroll
      for (int qq = 0; qq < 4; ++qq) {
        int x0 = t32[(q * 16 + qq * 4 + 0) * W_IN + w];
        int x1 = t32[(q * 16 + qq * 4 + 1) * W_IN + w];
        int x2 = t32[(q * 16 + qq * 4 + 2) * W_IN + w];
        int x3 = t32[(q * 16 + qq * 4 + 3) * W_IN + w];
        b[qq] = (x0 & 255) | ((x1 & 255) << 8) | ((x2 & 255) << 16) | ((x3 & 255) << 24);
        srow = dot4(b[qq], 0x01010101, srow);
      }
      *(int4*)(dst + (size_t)q * 1024 + w * 16) = *(int4*)b;
      atomicAdd(&rsum[w], srow);
    }
  }
  __syncthreads();
  if (tid < W_IN) rs[((size_t)n * H_IN + h) * W_IN + tid] = rsum[tid];
}

// ---------------- per-output-pixel: asumf = -3e-4 * receptive-field sum
__global__ void asum_k(const int* __restrict__ rs, float* __restrict__ asumf) {
  int px = blockIdx.x * 256 + threadIdx.x;
  if (px >= NPX) return;
  int n = px / PXROW, rem = px - n * PXROW;
  int y = rem / W_OUT, x = rem - y * W_OUT;
  const int* rp = rs + ((size_t)n * H_IN + y) * W_IN + x;
  int s = 0;
#pragma unroll
  for (int kh = 0; kh < 3; ++kh)
    s += rp[kh * W_IN + 0] + rp[kh * W_IN + 1] + rp[kh * W_IN + 2];
  asumf[px] = -3e-4f * (float)s;
}

__device__ __forceinline__ int mklb(int pf, int pxl, int c16) {
  int j = pf * 16 + pxl;
  int jc = j > 107 ? 107 : j;
  int dy = (jc >= 54) ? 1 : 0;
  return c16 * 4096 + dy * 1024 + (jc - dy * 54) * 16;
}

// ---------------- main MFMA conv
__launch_bounds__(256, 5)
__global__ void conv_mfma(const signed char* __restrict__ ip2,
                          const signed char* __restrict__ wq3,
                          const float* __restrict__ asumf,
                          const float* __restrict__ bconst,
                          float* __restrict__ out) {
  __shared__ signed char lds[32768];   // [plane i(8)=ci/16][row(4)][w(64)][16B]
  const int tid = threadIdx.x, w = tid >> 6, l = tid & 63;
  const int c16 = l >> 4, pxl = l & 15;

  // XCD swizzle: 3456 = 8 xcd * 432; co-quarters of one slab stay on one XCD
  const int b0 = blockIdx.x;
  const int wg = (b0 & 7) * 432 + (b0 >> 3);
  const int cq = wg & 3;               // co quarter 0..3
  const int nr = wg >> 2;              // n*27 + rp
  const int n  = nr / 27;
  const int rp = nr - n * 27;
  const int y0 = rp * 2;

  // ---- stage slab DENSE (4 input rows, 32KB incl w=56..63 junk, reads clamped)
  const signed char* ipn = ip2 + ((size_t)n * H_IN + y0) * 8192;
  {
    const int r = tid >> 6;
    const int off = (tid & 63) * 16;
    const signed char* src = ipn + (size_t)r * 8192 + off;
#pragma unroll
    for (int i = 0; i < 8; ++i)
      gload16(src + (size_t)i * 1024, &lds[i * 4096 + tid * 16]);
  }

  // ---- per-lane B pixel bases: pf covers px j = pf*16 + pxl (112 px tile)
  const int lb0 = mklb(0, pxl, c16), lb1 = mklb(1, pxl, c16), lb2 = mklb(2, pxl, c16),
            lb3 = mklb(3, pxl, c16), lb4 = mklb(4, pxl, c16), lb5 = mklb(5, pxl, c16),
            lb6 = mklb(6, pxl, c16);

  // ---- A source: co = cq*64 + w*16 + pxl, k-chunk c16; frag(ks) at +ks*16384
  const signed char* awq = wq3 + (size_t)c16 * 4096 +
                           (size_t)(cq * 64 + w * 16 + pxl) * 16;

  i32x4 acc0 = {0,0,0,0}, acc1 = {0,0,0,0}, acc2 = {0,0,0,0}, acc3 = {0,0,0,0},
        acc4 = {0,0,0,0}, acc5 = {0,0,0,0}, acc6 = {0,0,0,0};
  i32x4 aX, aY, aZ;

  aX = *(const i32x4*)(awq);
  aY = *(const i32x4*)(awq + 16384);
  __syncthreads();   // slab staged — the ONLY barrier

#define KSTEP(ks, AU, AL, DOLOAD)                                              \
  {                                                                            \
    if (DOLOAD) AL = *(const i32x4*)(awq + (size_t)((ks) + 2) * 16384);        \
    __builtin_amdgcn_sched_barrier(0);                                         \
    constexpr int d_ = ((ks) & 1) * 16384 + (((ks) >> 1) / 3) * 1024 +         \
                       (((ks) >> 1) % 3) * 16;                                 \
    i32x4 q0 = *(const i32x4*)(&lds[lb0 + d_]);                                \
    i32x4 q1 = *(const i32x4*)(&lds[lb1 + d_]);                                \
    i32x4 q2 = *(const i32x4*)(&lds[lb2 + d_]);                                \
    i32x4 q3 = *(const i32x4*)(&lds[lb3 + d_]);                                \
    i32x4 q4 = *(const i32x4*)(&lds[lb4 + d_]);                                \
    i32x4 q5 = *(const i32x4*)(&lds[lb5 + d_]);                                \
    i32x4 q6 = *(const i32x4*)(&lds[lb6 + d_]);                                \
    __builtin_amdgcn_s_setprio(1);                                             \
    acc0 = __builtin_amdgcn_mfma_i32_16x16x64_i8(AU, q0, acc0, 0, 0, 0);       \
    acc1 = __builtin_amdgcn_mfma_i32_16x16x64_i8(AU, q1, acc1, 0, 0, 0);       \
    acc2 = __builtin_amdgcn_mfma_i32_16x16x64_i8(AU, q2, acc2, 0, 0, 0);       \
    acc3 = __builtin_amdgcn_mfma_i32_16x16x64_i8(AU, q3, acc3, 0, 0, 0);       \
    acc4 = __builtin_amdgcn_mfma_i32_16x16x64_i8(AU, q4, acc4, 0, 0, 0);       \
    acc5 = __builtin_amdgcn_mfma_i32_16x16x64_i8(AU, q5, acc5, 0, 0, 0);       \
    acc6 = __builtin_amdgcn_mfma_i32_16x16x64_i8(AU, q6, acc6, 0, 0, 0);       \
    __builtin_amdgcn_s_setprio(0);                                             \
  }

  // 18 ksteps (t = ks>>1, s = ks&1); A triple-buffer: use ks%3, load (ks+2)%3
  KSTEP(0,  aX, aZ, 1)  KSTEP(1,  aY, aX, 1)  KSTEP(2,  aZ, aY, 1)
  KSTEP(3,  aX, aZ, 1)  KSTEP(4,  aY, aX, 1)  KSTEP(5,  aZ, aY, 1)
  KSTEP(6,  aX, aZ, 1)  KSTEP(7,  aY, aX, 1)  KSTEP(8,  aZ, aY, 1)
  KSTEP(9,  aX, aZ, 1)  KSTEP(10, aY, aX, 1)  KSTEP(11, aZ, aY, 1)
  KSTEP(12, aX, aZ, 1)  KSTEP(13, aY, aX, 1)  KSTEP(14, aZ, aY, 1)
  KSTEP(15, aX, aZ, 1)  KSTEP(16, aY, aX, 0)  KSTEP(17, aZ, aY, 0)
#undef KSTEP

  // ---- epilogue: C frag 16x16: px col = l&15, co row = c16*4 + j
  float* obase = out + ((size_t)n * C_OUT + cq * 64) * PXROW + y0 * W_OUT;
  const float* apx = asumf + (size_t)n * PXROW + y0 * W_OUT;
  const float asf0 = apx[pxl];
  const float asf1 = apx[16 + pxl];
  const float asf2 = apx[32 + pxl];
  const float asf3 = apx[48 + pxl];
  const float asf4 = apx[64 + pxl];
  const float asf5 = apx[80 + pxl];
  const int j6 = 96 + pxl;
  const float asf6 = (j6 < 108) ? apx[j6] : 0.0f;
#pragma unroll
  for (int j = 0; j < 4; ++j) {
    int co = w * 16 + c16 * 4 + j;            // co within 64-co block
    float bc = bconst[cq * 64 + co];
    float* o = obase + (size_t)co * PXROW;
    o[pxl]      = 1e-4f * (float)acc0[j] + asf0 + bc;
    o[16 + pxl] = 1e-4f * (float)acc1[j] + asf1 + bc;
    o[32 + pxl] = 1e-4f * (float)acc2[j] + asf2 + bc;
    o[48 + pxl] = 1e-4f * (float)acc3[j] + asf3 + bc;
    o[64 + pxl] = 1e-4f * (float)acc4[j] + asf4 + bc;
    o[80 + pxl] = 1e-4f * (float)acc5[j] + asf5 + bc;
    if (j6 < 108)
      o[j6] = 1e-4f * (float)acc6[j] + asf6 + bc;
  }
}

// ---------------- fallback (tiny ws): naive direct conv
__global__ void conv_naive(const int* __restrict__ in, const int* __restrict__ w,
                           const float* __restrict__ bias, float* __restrict__ out) {
  size_t idx = (size_t)blockIdx.x * 256 + threadIdx.x;
  size_t total = (size_t)N_B * C_OUT * H_OUT * W_OUT;
  if (idx >= total) return;
  int x = idx % W_OUT; size_t t = idx / W_OUT;
  int y = t % H_OUT; t /= H_OUT;
  int co = t % C_OUT; int n = (int)(t / C_OUT);
  int acc = 0;
  for (int ci = 0; ci < C_IN; ++ci) {
    const int* ib = in + (((size_t)n * C_IN + ci) * H_IN + y) * W_IN + x;
    const int* wb = w + (((size_t)co * C_IN + ci) * 3) * 3;
    for (int kh = 0; kh < 3; ++kh)
      for (int kw = 0; kw < 3; ++kw)
        acc += (ib[kh * W_IN + kw] - 7) * (wb[kh * 3 + kw] - 3);
  }
  float r = rintf(bias[co] / 0.0001f);
  r = fminf(fmaxf(r, -2147483648.0f), 2147483647.0f);
  out[idx] = (float)acc * (0.01f * 0.01f) + r * 0.0001f;
}

extern "C" void kernel_launch(void* const* d_in, const int* in_sizes, int n_in,
                              void* d_out, int out_size, void* d_ws, size_t ws_size,
                              hipStream_t stream) {
  const int*   in   = (const int*)d_in[0];
  const int*   w    = (const int*)d_in[1];
  const float* bias = (const float*)d_in[2];
  float*       out  = (float*)d_out;

  const size_t WQ_OFF = 0;                          // 294912
  const size_t IP_OFF = 294912;                     // 32*56*8192 = 14680064
  const size_t RS_OFF = IP_OFF + 14680064;          // 401408
  const size_t AF_OFF = RS_OFF + 401408;            // 373248
  const size_t BC_OFF = AF_OFF + 373248;            // 1024
  const size_t NEED   = BC_OFF + 1024;              // ~15.75 MB

  if (ws_size >= NEED) {
    char* ws = (char*)d_ws;
    signed char* wq3  = (signed char*)(ws + WQ_OFF);
    signed char* ip2  = (signed char*)(ws + IP_OFF);
    int*         rs   = (int*)(ws + RS_OFF);
    float*       af   = (float*)(ws + AF_OFF);
    float*       bc   = (float*)(ws + BC_OFF);

    repack_w<<<C_OUT, 128, 0, stream>>>(w, bias, wq3, bc);
    repack_in<<<dim3(H_IN, N_B), 256, 0, stream>>>(in, ip2, rs);
    asum_k<<<(NPX + 255) / 256, 256, 0, stream>>>(rs, af);
    conv_mfma<<<3456, 256, 0, stream>>>(ip2, wq3, af, bc, out);
  } else {
    size_t total = (size_t)N_B * C_OUT * H_OUT * W_OUT;
    conv_naive<<<(total + 255) / 256, 256, 0, stream>>>(in, w, bias, out);
  }
}

// Round 11
// 56.215 us; speedup vs baseline: 1.4242x; 1.0404x over previous
//
#include <hip/hip_runtime.h>
#include <hip/hip_bf16.h>

// Quantized int8 3x3 conv via implicit-im2col MFMA (mfma_i32_16x16x64_i8).
// out = 1e-4*dot + asumf[px] + bconst[co]
//
// Round-11 structure:
//   - wave tile 32co x 112px (m2 x p7): each B ds_read feeds 2 MFMAs ->
//     B LDS volume halves vs R10 (0.87GB ~ 17us), the measured R10 wall
//   - block 128co x 112px, 4 waves; grid 1728 = 8 XCD x 216 chunked swizzle
//   - A: L2->regs, 2 frags/kstep, register double-buffer, SB-pinned
//   - ~115 VGPR -> launch_bounds(256,4): 4 blocks/CU (128KB LDS), 16 waves/CU
//   - input slab ip2[n][h][q8][w64][16B] staged dense once; no loop barriers

#define N_B   32
#define C_IN  128
#define H_IN  56
#define W_IN  56
#define C_OUT 256
#define H_OUT 54
#define W_OUT 54
#define K_TOT 1152
#define NPX   (N_B * H_OUT * W_OUT)   // 93312
#define PXROW (H_OUT * W_OUT)         // 2916

using i32x4  = __attribute__((ext_vector_type(4))) int;

static __device__ __forceinline__ int dot4(int a, int b, int c) {
#if __has_builtin(__builtin_amdgcn_sdot4)
  return __builtin_amdgcn_sdot4(a, b, c, false);
#else
  signed char a0 = (signed char)a, a1 = (signed char)(a >> 8),
              a2 = (signed char)(a >> 16), a3 = (signed char)(a >> 24);
  signed char b0 = (signed char)b, b1 = (signed char)(b >> 8),
              b2 = (signed char)(b >> 16), b3 = (signed char)(b >> 24);
  return c + a0 * b0 + a1 * b1 + a2 * b2 + a3 * b3;
#endif
}

__device__ __forceinline__ void gload16(const void* g, void* l) {
  __builtin_amdgcn_global_load_lds(
      (const __attribute__((address_space(1))) void*)g,
      (__attribute__((address_space(3))) void*)l, 16, 0, 0);
}

// ---------------- weight repack: OIHW(int32) -> wq3[t][kk][h][co][16] i8, bconst
// 16x16x64 fragment view: offset = ks*16384 + c16*4096 + co*16
__global__ void repack_w(const int* __restrict__ w, const float* __restrict__ bias,
                         signed char* __restrict__ wq3, float* __restrict__ bconst) {
  int co = blockIdx.x;    // 256
  int ci = threadIdx.x;   // 128
  const int* wrow = w + (size_t)co * K_TOT + (size_t)ci * 9;
  int s = 0;
  int kk = ci >> 5, h = (ci >> 4) & 1, b = ci & 15;
  size_t base = (size_t)kk * 8192 + h * 4096 + co * 16 + b;
#pragma unroll
  for (int t = 0; t < 9; ++t) {
    int v = wrow[t];
    s += v;
    wq3[(size_t)t * 32768 + base] = (signed char)v;
  }
  __shared__ int red[128];
  red[ci] = s;
  __syncthreads();
  for (int off = 64; off > 0; off >>= 1) {
    if (ci < off) red[ci] += red[ci + off];
    __syncthreads();
  }
  if (ci == 0) {
    int wsum = red[0];
    float r = rintf(bias[co] / 0.0001f);                 // round half-even
    r = fminf(fmaxf(r, -2147483648.0f), 2147483647.0f);  // clamp to i32 range
    bconst[co] = 1e-4f * (float)(-7 * wsum + 24192) + r * 0.0001f;
  }
}

// ---------------- input repack: NCHW(int32) -> ip2[n][h][q8][w64][16B] i8 + rowsums
__global__ void repack_in(const int* __restrict__ in, signed char* __restrict__ ip2,
                          int* __restrict__ rs) {
  __shared__ int t32[C_IN * W_IN];   // 28KB
  __shared__ int rsum[W_IN];
  int h = blockIdx.x, n = blockIdx.y;
  int tid = threadIdx.x;             // 256
  if (tid < W_IN) rsum[tid] = 0;

  int ci = tid >> 1, hf = tid & 1;
  const int* s = in + ((size_t)n * C_IN + ci) * (H_IN * W_IN) + h * W_IN + hf * 28;
  int* d = &t32[ci * W_IN + hf * 28];
#pragma unroll
  for (int k = 0; k < 7; ++k)
    *(int4*)(d + k * 4) = *(const int4*)(s + k * 4);
  __syncthreads();

  signed char* dst = ip2 + ((size_t)n * H_IN + h) * 8192;
#pragma unroll
  for (int jj = 0; jj < 2; ++jj) {
    int j = jj * 256 + tid;          // 0..511: q = j>>6, w = j&63
    int q = j >> 6, w = j & 63;
    if (w < W_IN) {
      int b[4], srow = 0;
#pragma unroll
      for (int qq = 0; qq < 4; ++qq) {
        int x0 = t32[(q * 16 + qq * 4 + 0) * W_IN + w];
        int x1 = t32[(q * 16 + qq * 4 + 1) * W_IN + w];
        int x2 = t32[(q * 16 + qq * 4 + 2) * W_IN + w];
        int x3 = t32[(q * 16 + qq * 4 + 3) * W_IN + w];
        b[qq] = (x0 & 255) | ((x1 & 255) << 8) | ((x2 & 255) << 16) | ((x3 & 255) << 24);
        srow = dot4(b[qq], 0x01010101, srow);
      }
      *(int4*)(dst + (size_t)q * 1024 + w * 16) = *(int4*)b;
      atomicAdd(&rsum[w], srow);
    }
  }
  __syncthreads();
  if (tid < W_IN) rs[((size_t)n * H_IN + h) * W_IN + tid] = rsum[tid];
}

// ---------------- per-output-pixel: asumf = -3e-4 * receptive-field sum
__global__ void asum_k(const int* __restrict__ rs, float* __restrict__ asumf) {
  int px = blockIdx.x * 256 + threadIdx.x;
  if (px >= NPX) return;
  int n = px / PXROW, rem = px - n * PXROW;
  int y = rem / W_OUT, x = rem - y * W_OUT;
  const int* rp = rs + ((size_t)n * H_IN + y) * W_IN + x;
  int s = 0;
#pragma unroll
  for (int kh = 0; kh < 3; ++kh)
    s += rp[kh * W_IN + 0] + rp[kh * W_IN + 1] + rp[kh * W_IN + 2];
  asumf[px] = -3e-4f * (float)s;
}

__device__ __forceinline__ int mklb(int pf, int pxl, int c16) {
  int j = pf * 16 + pxl;
  int jc = j > 107 ? 107 : j;
  int dy = (jc >= 54) ? 1 : 0;
  return c16 * 4096 + dy * 1024 + (jc - dy * 54) * 16;
}

// ---------------- main MFMA conv
__launch_bounds__(256, 4)
__global__ void conv_mfma(const signed char* __restrict__ ip2,
                          const signed char* __restrict__ wq3,
                          const float* __restrict__ asumf,
                          const float* __restrict__ bconst,
                          float* __restrict__ out) {
  __shared__ signed char lds[32768];   // [plane i(8)=ci/16][row(4)][w(64)][16B]
  const int tid = threadIdx.x, w = tid >> 6, l = tid & 63;
  const int c16 = l >> 4, pxl = l & 15;

  // chunked XCD swizzle: 1728 = 8 xcd * 216 (ct-pairs/rows share an XCD's L2)
  const int b0 = blockIdx.x;
  const int wg = (b0 & 7) * 216 + (b0 >> 3);
  const int cq = wg & 1;               // co half 0..1
  const int nr = wg >> 1;              // n*27 + rp
  const int n  = nr / 27;
  const int rp = nr - n * 27;
  const int y0 = rp * 2;

  // ---- stage slab DENSE (4 input rows, 32KB)
  const signed char* ipn = ip2 + ((size_t)n * H_IN + y0) * 8192;
  {
    const int r = tid >> 6;
    const int off = (tid & 63) * 16;
    const signed char* src = ipn + (size_t)r * 8192 + off;
#pragma unroll
    for (int i = 0; i < 8; ++i)
      gload16(src + (size_t)i * 1024, &lds[i * 4096 + tid * 16]);
  }

  // ---- per-lane B pixel bases: pf covers px j = pf*16 + pxl (112 px tile)
  const int lb0 = mklb(0, pxl, c16), lb1 = mklb(1, pxl, c16), lb2 = mklb(2, pxl, c16),
            lb3 = mklb(3, pxl, c16), lb4 = mklb(4, pxl, c16), lb5 = mklb(5, pxl, c16),
            lb6 = mklb(6, pxl, c16);

  // ---- A source: co = cq*128 + w*32 + m*16 + pxl, k-chunk c16
  const signed char* awq = wq3 + (size_t)c16 * 4096 +
                           (size_t)(cq * 128 + w * 32 + pxl) * 16;

  i32x4 a0_0 = {0,0,0,0}, a0_1 = {0,0,0,0}, a0_2 = {0,0,0,0}, a0_3 = {0,0,0,0},
        a0_4 = {0,0,0,0}, a0_5 = {0,0,0,0}, a0_6 = {0,0,0,0};
  i32x4 a1_0 = {0,0,0,0}, a1_1 = {0,0,0,0}, a1_2 = {0,0,0,0}, a1_3 = {0,0,0,0},
        a1_4 = {0,0,0,0}, a1_5 = {0,0,0,0}, a1_6 = {0,0,0,0};
  i32x4 wa0, wa1, wb0, wb1;

#define LDW(P, t)                                                              \
  P##0 = *(const i32x4*)(awq + (size_t)(t) * 16384);                           \
  P##1 = *(const i32x4*)(awq + (size_t)(t) * 16384 + 256);

  LDW(wa, 0);
  __syncthreads();   // slab staged — the ONLY barrier

#define KSTEP(ks, U, L, DOLOAD)                                                \
  {                                                                            \
    if (DOLOAD) { LDW(L, (ks) + 1); }                                          \
    __builtin_amdgcn_sched_barrier(0);                                         \
    constexpr int d_ = ((ks) & 1) * 16384 + (((ks) >> 1) / 3) * 1024 +         \
                       (((ks) >> 1) % 3) * 16;                                 \
    i32x4 q0 = *(const i32x4*)(&lds[lb0 + d_]);                                \
    i32x4 q1 = *(const i32x4*)(&lds[lb1 + d_]);                                \
    i32x4 q2 = *(const i32x4*)(&lds[lb2 + d_]);                                \
    i32x4 q3 = *(const i32x4*)(&lds[lb3 + d_]);                                \
    i32x4 q4 = *(const i32x4*)(&lds[lb4 + d_]);                                \
    i32x4 q5 = *(const i32x4*)(&lds[lb5 + d_]);                                \
    i32x4 q6 = *(const i32x4*)(&lds[lb6 + d_]);                                \
    __builtin_amdgcn_s_setprio(1);                                             \
    a0_0 = __builtin_amdgcn_mfma_i32_16x16x64_i8(U##0, q0, a0_0, 0, 0, 0);     \
    a1_0 = __builtin_amdgcn_mfma_i32_16x16x64_i8(U##1, q0, a1_0, 0, 0, 0);     \
    a0_1 = __builtin_amdgcn_mfma_i32_16x16x64_i8(U##0, q1, a0_1, 0, 0, 0);     \
    a1_1 = __builtin_amdgcn_mfma_i32_16x16x64_i8(U##1, q1, a1_1, 0, 0, 0);     \
    a0_2 = __builtin_amdgcn_mfma_i32_16x16x64_i8(U##0, q2, a0_2, 0, 0, 0);     \
    a1_2 = __builtin_amdgcn_mfma_i32_16x16x64_i8(U##1, q2, a1_2, 0, 0, 0);     \
    a0_3 = __builtin_amdgcn_mfma_i32_16x16x64_i8(U##0, q3, a0_3, 0, 0, 0);     \
    a1_3 = __builtin_amdgcn_mfma_i32_16x16x64_i8(U##1, q3, a1_3, 0, 0, 0);     \
    a0_4 = __builtin_amdgcn_mfma_i32_16x16x64_i8(U##0, q4, a0_4, 0, 0, 0);     \
    a1_4 = __builtin_amdgcn_mfma_i32_16x16x64_i8(U##1, q4, a1_4, 0, 0, 0);     \
    a0_5 = __builtin_amdgcn_mfma_i32_16x16x64_i8(U##0, q5, a0_5, 0, 0, 0);     \
    a1_5 = __builtin_amdgcn_mfma_i32_16x16x64_i8(U##1, q5, a1_5, 0, 0, 0);     \
    a0_6 = __builtin_amdgcn_mfma_i32_16x16x64_i8(U##0, q6, a0_6, 0, 0, 0);     \
    a1_6 = __builtin_amdgcn_mfma_i32_16x16x64_i8(U##1, q6, a1_6, 0, 0, 0);     \
    __builtin_amdgcn_s_setprio(0);                                             \
  }

  KSTEP(0,  wa, wb, 1)  KSTEP(1,  wb, wa, 1)  KSTEP(2,  wa, wb, 1)
  KSTEP(3,  wb, wa, 1)  KSTEP(4,  wa, wb, 1)  KSTEP(5,  wb, wa, 1)
  KSTEP(6,  wa, wb, 1)  KSTEP(7,  wb, wa, 1)  KSTEP(8,  wa, wb, 1)
  KSTEP(9,  wb, wa, 1)  KSTEP(10, wa, wb, 1)  KSTEP(11, wb, wa, 1)
  KSTEP(12, wa, wb, 1)  KSTEP(13, wb, wa, 1)  KSTEP(14, wa, wb, 1)
  KSTEP(15, wb, wa, 1)  KSTEP(16, wa, wb, 1)  KSTEP(17, wb, wa, 0)
#undef KSTEP
#undef LDW

  // ---- epilogue: C frag 16x16: px col = pxl, co row = c16*4 + j (+ m*16)
  float* obase = out + ((size_t)n * C_OUT + cq * 128) * PXROW + y0 * W_OUT;
  const float* apx = asumf + (size_t)n * PXROW + y0 * W_OUT;
  const float asf0 = apx[pxl];
  const float asf1 = apx[16 + pxl];
  const float asf2 = apx[32 + pxl];
  const float asf3 = apx[48 + pxl];
  const float asf4 = apx[64 + pxl];
  const float asf5 = apx[80 + pxl];
  const int j6 = 96 + pxl;
  const float asf6 = (j6 < 108) ? apx[j6] : 0.0f;
#pragma unroll
  for (int m = 0; m < 2; ++m) {
#pragma unroll
    for (int j = 0; j < 4; ++j) {
      int co = w * 32 + m * 16 + c16 * 4 + j;   // co within 128-co block
      float bc = bconst[cq * 128 + co];
      float* o = obase + (size_t)co * PXROW;
      const i32x4& v0 = m ? a1_0 : a0_0;
      const i32x4& v1 = m ? a1_1 : a0_1;
      const i32x4& v2 = m ? a1_2 : a0_2;
      const i32x4& v3 = m ? a1_3 : a0_3;
      const i32x4& v4 = m ? a1_4 : a0_4;
      const i32x4& v5 = m ? a1_5 : a0_5;
      const i32x4& v6 = m ? a1_6 : a0_6;
      o[pxl]      = 1e-4f * (float)v0[j] + asf0 + bc;
      o[16 + pxl] = 1e-4f * (float)v1[j] + asf1 + bc;
      o[32 + pxl] = 1e-4f * (float)v2[j] + asf2 + bc;
      o[48 + pxl] = 1e-4f * (float)v3[j] + asf3 + bc;
      o[64 + pxl] = 1e-4f * (float)v4[j] + asf4 + bc;
      o[80 + pxl] = 1e-4f * (float)v5[j] + asf5 + bc;
      if (j6 < 108)
        o[j6] = 1e-4f * (float)v6[j] + asf6 + bc;
    }
  }
}

// ---------------- fallback (tiny ws): naive direct conv
__global__ void conv_naive(const int* __restrict__ in, const int* __restrict__ w,
                           const float* __restrict__ bias, float* __restrict__ out) {
  size_t idx = (size_t)blockIdx.x * 256 + threadIdx.x;
  size_t total = (size_t)N_B * C_OUT * H_OUT * W_OUT;
  if (idx >= total) return;
  int x = idx % W_OUT; size_t t = idx / W_OUT;
  int y = t % H_OUT; t /= H_OUT;
  int co = t % C_OUT; int n = (int)(t / C_OUT);
  int acc = 0;
  for (int ci = 0; ci < C_IN; ++ci) {
    const int* ib = in + (((size_t)n * C_IN + ci) * H_IN + y) * W_IN + x;
    const int* wb = w + (((size_t)co * C_IN + ci) * 3) * 3;
    for (int kh = 0; kh < 3; ++kh)
      for (int kw = 0; kw < 3; ++kw)
        acc += (ib[kh * W_IN + kw] - 7) * (wb[kh * 3 + kw] - 3);
  }
  float r = rintf(bias[co] / 0.0001f);
  r = fminf(fmaxf(r, -2147483648.0f), 2147483647.0f);
  out[idx] = (float)acc * (0.01f * 0.01f) + r * 0.0001f;
}

extern "C" void kernel_launch(void* const* d_in, const int* in_sizes, int n_in,
                              void* d_out, int out_size, void* d_ws, size_t ws_size,
                              hipStream_t stream) {
  const int*   in   = (const int*)d_in[0];
  const int*   w    = (const int*)d_in[1];
  const float* bias = (const float*)d_in[2];
  float*       out  = (float*)d_out;

  const size_t WQ_OFF = 0;                          // 294912
  const size_t IP_OFF = 294912;                     // 32*56*8192 = 14680064
  const size_t RS_OFF = IP_OFF + 14680064;          // 401408
  const size_t AF_OFF = RS_OFF + 401408;            // 373248
  const size_t BC_OFF = AF_OFF + 373248;            // 1024
  const size_t NEED   = BC_OFF + 1024;              // ~15.75 MB

  if (ws_size >= NEED) {
    char* ws = (char*)d_ws;
    signed char* wq3  = (signed char*)(ws + WQ_OFF);
    signed char* ip2  = (signed char*)(ws + IP_OFF);
    int*         rs   = (int*)(ws + RS_OFF);
    float*       af   = (float*)(ws + AF_OFF);
    float*       bc   = (float*)(ws + BC_OFF);

    repack_w<<<C_OUT, 128, 0, stream>>>(w, bias, wq3, bc);
    repack_in<<<dim3(H_IN, N_B), 256, 0, stream>>>(in, ip2, rs);
    asum_k<<<(NPX + 255) / 256, 256, 0, stream>>>(rs, af);
    conv_mfma<<<1728, 256, 0, stream>>>(ip2, wq3, af, bc, out);
  } else {
    size_t total = (size_t)N_B * C_OUT * H_OUT * W_OUT;
    conv_naive<<<(total + 255) / 256, 256, 0, stream>>>(in, w, bias, out);
  }
}

// Round 12
// 50.483 us; speedup vs baseline: 1.5860x; 1.1135x over previous
//
#include <hip/hip_runtime.h>
#include <hip/hip_bf16.h>

// Quantized int8 3x3 conv via implicit-im2col MFMA (mfma_i32_16x16x64_i8).
// out = 1e-4*dot + asumf[px] + bconst[co]
//
// Round-12 structure (R11 core + two fixes):
//   - VGPR trim: B-fragment reads split 4+3 (max 4 q live) -> ~100 VGPR,
//     below the 128 cliff where waves/CU halve 16->8
//   - launch fusion: prep = repack_in(1792 blk) + repack_w(128 blk) one kernel;
//     asum folded INTO conv prologue (asf_lds[112] from rs) -> 2 launches total
//   - wave tile 32co x 112px (m2 x p7), block 128co x 112px, 4 waves
//   - A: L2->regs, 2 frags/kstep, named double-buffer, SB-pinned
//   - input slab ip2[n][h][q8][w64][16B] staged dense once; no loop barriers
//   - chunked XCD swizzle 1728 = 8 x 216

#define N_B   32
#define C_IN  128
#define H_IN  56
#define W_IN  56
#define C_OUT 256
#define H_OUT 54
#define W_OUT 54
#define K_TOT 1152
#define NPX   (N_B * H_OUT * W_OUT)   // 93312
#define PXROW (H_OUT * W_OUT)         // 2916

using i32x4  = __attribute__((ext_vector_type(4))) int;

static __device__ __forceinline__ int dot4(int a, int b, int c) {
#if __has_builtin(__builtin_amdgcn_sdot4)
  return __builtin_amdgcn_sdot4(a, b, c, false);
#else
  signed char a0 = (signed char)a, a1 = (signed char)(a >> 8),
              a2 = (signed char)(a >> 16), a3 = (signed char)(a >> 24);
  signed char b0 = (signed char)b, b1 = (signed char)(b >> 8),
              b2 = (signed char)(b >> 16), b3 = (signed char)(b >> 24);
  return c + a0 * b0 + a1 * b1 + a2 * b2 + a3 * b3;
#endif
}

__device__ __forceinline__ void gload16(const void* g, void* l) {
  __builtin_amdgcn_global_load_lds(
      (const __attribute__((address_space(1))) void*)g,
      (__attribute__((address_space(3))) void*)l, 16, 0, 0);
}

// ---------------- fused prep:
//   blocks [0,1792): repack_in  NCHW(int32) -> ip2[n][h][q8][w64][16B] + rs
//   blocks [1792,1920): repack_w (2 co per block) -> wq3 + bconst
__global__ void prep(const int* __restrict__ in, const int* __restrict__ wsrc,
                     const float* __restrict__ bias,
                     signed char* __restrict__ ip2, int* __restrict__ rs,
                     signed char* __restrict__ wq3, float* __restrict__ bconst) {
  const int bid = blockIdx.x, tid = threadIdx.x;
  __shared__ int t32[C_IN * W_IN];   // 28KB (repack_in) / red[256] aliased below
  __shared__ int rsum[W_IN];

  if (bid < 1792) {
    // ---- repack_in: h = bid % 56, n = bid / 56
    const int h = bid % 56, n = bid / 56;
    if (tid < W_IN) rsum[tid] = 0;
    int ci = tid >> 1, hf = tid & 1;
    const int* s = in + ((size_t)n * C_IN + ci) * (H_IN * W_IN) + h * W_IN + hf * 28;
    int* d = &t32[ci * W_IN + hf * 28];
#pragma unroll
    for (int k = 0; k < 7; ++k)
      *(int4*)(d + k * 4) = *(const int4*)(s + k * 4);
    __syncthreads();

    signed char* dst = ip2 + ((size_t)n * H_IN + h) * 8192;
#pragma unroll
    for (int jj = 0; jj < 2; ++jj) {
      int j = jj * 256 + tid;          // 0..511: q = j>>6, w = j&63
      int q = j >> 6, w = j & 63;
      if (w < W_IN) {
        int b[4], srow = 0;
#pragma unroll
        for (int qq = 0; qq < 4; ++qq) {
          int x0 = t32[(q * 16 + qq * 4 + 0) * W_IN + w];
          int x1 = t32[(q * 16 + qq * 4 + 1) * W_IN + w];
          int x2 = t32[(q * 16 + qq * 4 + 2) * W_IN + w];
          int x3 = t32[(q * 16 + qq * 4 + 3) * W_IN + w];
          b[qq] = (x0 & 255) | ((x1 & 255) << 8) | ((x2 & 255) << 16) | ((x3 & 255) << 24);
          srow = dot4(b[qq], 0x01010101, srow);
        }
        *(int4*)(dst + (size_t)q * 1024 + w * 16) = *(int4*)b;
        atomicAdd(&rsum[w], srow);
      }
    }
    __syncthreads();
    if (tid < W_IN) rs[((size_t)n * H_IN + h) * W_IN + tid] = rsum[tid];
  } else {
    // ---- repack_w: co = (bid-1792)*2 + (tid>>7), ci = tid&127
    int* red = t32;                     // alias, first 256 ints
    const int co = (bid - 1792) * 2 + (tid >> 7);
    const int ci = tid & 127;
    const int* wrow = wsrc + (size_t)co * K_TOT + (size_t)ci * 9;
    int s = 0;
    int kk = ci >> 5, hh = (ci >> 4) & 1, b = ci & 15;
    size_t base = (size_t)kk * 8192 + hh * 4096 + co * 16 + b;
#pragma unroll
    for (int t = 0; t < 9; ++t) {
      int v = wrow[t];
      s += v;
      wq3[(size_t)t * 32768 + base] = (signed char)v;
    }
    red[tid] = s;
    __syncthreads();
    for (int off = 64; off > 0; off >>= 1) {
      if (ci < off) red[tid] += red[tid + off];
      __syncthreads();
    }
    if (ci == 0) {
      int wsum = red[tid];
      float r = rintf(bias[co] / 0.0001f);                 // round half-even
      r = fminf(fmaxf(r, -2147483648.0f), 2147483647.0f);  // clamp to i32 range
      bconst[co] = 1e-4f * (float)(-7 * wsum + 24192) + r * 0.0001f;
    }
  }
}

__device__ __forceinline__ int mklb(int pf, int pxl, int c16) {
  int j = pf * 16 + pxl;
  int jc = j > 107 ? 107 : j;
  int dy = (jc >= 54) ? 1 : 0;
  return c16 * 4096 + dy * 1024 + (jc - dy * 54) * 16;
}

// ---------------- main MFMA conv (asum folded in)
__launch_bounds__(256, 4)
__global__ void conv_mfma(const signed char* __restrict__ ip2,
                          const signed char* __restrict__ wq3,
                          const int* __restrict__ rs,
                          const float* __restrict__ bconst,
                          float* __restrict__ out) {
  __shared__ signed char lds[32768];   // [plane i(8)=ci/16][row(4)][w(64)][16B]
  __shared__ float asf_lds[112];
  const int tid = threadIdx.x, w = tid >> 6, l = tid & 63;
  const int c16 = l >> 4, pxl = l & 15;

  // chunked XCD swizzle: 1728 = 8 xcd * 216
  const int b0 = blockIdx.x;
  const int wg = (b0 & 7) * 216 + (b0 >> 3);
  const int cq = wg & 1;               // co half 0..1
  const int nr = wg >> 1;              // n*27 + rp
  const int n  = nr / 27;
  const int rp = nr - n * 27;
  const int y0 = rp * 2;

  // ---- stage slab DENSE (4 input rows, 32KB)
  const signed char* ipn = ip2 + ((size_t)n * H_IN + y0) * 8192;
  {
    const int r = tid >> 6;
    const int off = (tid & 63) * 16;
    const signed char* src = ipn + (size_t)r * 8192 + off;
#pragma unroll
    for (int i = 0; i < 8; ++i)
      gload16(src + (size_t)i * 1024, &lds[i * 4096 + tid * 16]);
  }

  // ---- inline asum: asf_lds[j] = -3e-4 * sum of 3x3 rs window (L2-hot)
  if (tid < 108) {
    int dy = (tid >= 54) ? 1 : 0;
    int x  = tid - dy * 54;
    const int* rp_ = rs + ((size_t)n * H_IN + y0 + dy) * W_IN + x;
    int s = 0;
#pragma unroll
    for (int kh = 0; kh < 3; ++kh)
      s += rp_[kh * W_IN + 0] + rp_[kh * W_IN + 1] + rp_[kh * W_IN + 2];
    asf_lds[tid] = -3e-4f * (float)s;
  }

  // ---- per-lane B pixel bases: pf covers px j = pf*16 + pxl (112 px tile)
  const int lb0 = mklb(0, pxl, c16), lb1 = mklb(1, pxl, c16), lb2 = mklb(2, pxl, c16),
            lb3 = mklb(3, pxl, c16), lb4 = mklb(4, pxl, c16), lb5 = mklb(5, pxl, c16),
            lb6 = mklb(6, pxl, c16);

  // ---- A source: co = cq*128 + w*32 + m*16 + pxl, k-chunk c16
  const signed char* awq = wq3 + (size_t)c16 * 4096 +
                           (size_t)(cq * 128 + w * 32 + pxl) * 16;

  i32x4 a0_0 = {0,0,0,0}, a0_1 = {0,0,0,0}, a0_2 = {0,0,0,0}, a0_3 = {0,0,0,0},
        a0_4 = {0,0,0,0}, a0_5 = {0,0,0,0}, a0_6 = {0,0,0,0};
  i32x4 a1_0 = {0,0,0,0}, a1_1 = {0,0,0,0}, a1_2 = {0,0,0,0}, a1_3 = {0,0,0,0},
        a1_4 = {0,0,0,0}, a1_5 = {0,0,0,0}, a1_6 = {0,0,0,0};
  i32x4 wa0, wa1, wb0, wb1;

#define LDW(P, t)                                                              \
  P##0 = *(const i32x4*)(awq + (size_t)(t) * 16384);                           \
  P##1 = *(const i32x4*)(awq + (size_t)(t) * 16384 + 256);

  LDW(wa, 0);
  __syncthreads();   // slab + asf staged — the ONLY barrier

  // B reads split 4+3 so at most 4 q temps are live (VGPR < 128 cliff)
#define KSTEP(ks, U, L, DOLOAD)                                                \
  {                                                                            \
    if (DOLOAD) { LDW(L, (ks) + 1); }                                          \
    __builtin_amdgcn_sched_barrier(0);                                         \
    constexpr int d_ = ((ks) & 1) * 16384 + (((ks) >> 1) / 3) * 1024 +         \
                       (((ks) >> 1) % 3) * 16;                                 \
    {                                                                          \
      i32x4 q0 = *(const i32x4*)(&lds[lb0 + d_]);                              \
      i32x4 q1 = *(const i32x4*)(&lds[lb1 + d_]);                              \
      i32x4 q2 = *(const i32x4*)(&lds[lb2 + d_]);                              \
      i32x4 q3 = *(const i32x4*)(&lds[lb3 + d_]);                              \
      __builtin_amdgcn_s_setprio(1);                                           \
      a0_0 = __builtin_amdgcn_mfma_i32_16x16x64_i8(U##0, q0, a0_0, 0, 0, 0);   \
      a1_0 = __builtin_amdgcn_mfma_i32_16x16x64_i8(U##1, q0, a1_0, 0, 0, 0);   \
      a0_1 = __builtin_amdgcn_mfma_i32_16x16x64_i8(U##0, q1, a0_1, 0, 0, 0);   \
      a1_1 = __builtin_amdgcn_mfma_i32_16x16x64_i8(U##1, q1, a1_1, 0, 0, 0);   \
      a0_2 = __builtin_amdgcn_mfma_i32_16x16x64_i8(U##0, q2, a0_2, 0, 0, 0);   \
      a1_2 = __builtin_amdgcn_mfma_i32_16x16x64_i8(U##1, q2, a1_2, 0, 0, 0);   \
      a0_3 = __builtin_amdgcn_mfma_i32_16x16x64_i8(U##0, q3, a0_3, 0, 0, 0);   \
      a1_3 = __builtin_amdgcn_mfma_i32_16x16x64_i8(U##1, q3, a1_3, 0, 0, 0);   \
      __builtin_amdgcn_s_setprio(0);                                           \
    }                                                                          \
    __builtin_amdgcn_sched_barrier(0);                                         \
    {                                                                          \
      i32x4 q4 = *(const i32x4*)(&lds[lb4 + d_]);                              \
      i32x4 q5 = *(const i32x4*)(&lds[lb5 + d_]);                              \
      i32x4 q6 = *(const i32x4*)(&lds[lb6 + d_]);                              \
      __builtin_amdgcn_s_setprio(1);                                           \
      a0_4 = __builtin_amdgcn_mfma_i32_16x16x64_i8(U##0, q4, a0_4, 0, 0, 0);   \
      a1_4 = __builtin_amdgcn_mfma_i32_16x16x64_i8(U##1, q4, a1_4, 0, 0, 0);   \
      a0_5 = __builtin_amdgcn_mfma_i32_16x16x64_i8(U##0, q5, a0_5, 0, 0, 0);   \
      a1_5 = __builtin_amdgcn_mfma_i32_16x16x64_i8(U##1, q5, a1_5, 0, 0, 0);   \
      a0_6 = __builtin_amdgcn_mfma_i32_16x16x64_i8(U##0, q6, a0_6, 0, 0, 0);   \
      a1_6 = __builtin_amdgcn_mfma_i32_16x16x64_i8(U##1, q6, a1_6, 0, 0, 0);   \
      __builtin_amdgcn_s_setprio(0);                                           \
    }                                                                          \
  }

  KSTEP(0,  wa, wb, 1)  KSTEP(1,  wb, wa, 1)  KSTEP(2,  wa, wb, 1)
  KSTEP(3,  wb, wa, 1)  KSTEP(4,  wa, wb, 1)  KSTEP(5,  wb, wa, 1)
  KSTEP(6,  wa, wb, 1)  KSTEP(7,  wb, wa, 1)  KSTEP(8,  wa, wb, 1)
  KSTEP(9,  wb, wa, 1)  KSTEP(10, wa, wb, 1)  KSTEP(11, wb, wa, 1)
  KSTEP(12, wa, wb, 1)  KSTEP(13, wb, wa, 1)  KSTEP(14, wa, wb, 1)
  KSTEP(15, wb, wa, 1)  KSTEP(16, wa, wb, 1)  KSTEP(17, wb, wa, 0)
#undef KSTEP
#undef LDW

  // ---- epilogue: C frag 16x16: px col = pxl, co row = c16*4 + j (+ m*16)
  float* obase = out + ((size_t)n * C_OUT + cq * 128) * PXROW + y0 * W_OUT;
  const float asf0 = asf_lds[pxl];
  const float asf1 = asf_lds[16 + pxl];
  const float asf2 = asf_lds[32 + pxl];
  const float asf3 = asf_lds[48 + pxl];
  const float asf4 = asf_lds[64 + pxl];
  const float asf5 = asf_lds[80 + pxl];
  const int j6 = 96 + pxl;
  const float asf6 = (j6 < 108) ? asf_lds[j6] : 0.0f;
#pragma unroll
  for (int m = 0; m < 2; ++m) {
#pragma unroll
    for (int j = 0; j < 4; ++j) {
      int co = w * 32 + m * 16 + c16 * 4 + j;   // co within 128-co block
      float bc = bconst[cq * 128 + co];
      float* o = obase + (size_t)co * PXROW;
      const i32x4& v0 = m ? a1_0 : a0_0;
      const i32x4& v1 = m ? a1_1 : a0_1;
      const i32x4& v2 = m ? a1_2 : a0_2;
      const i32x4& v3 = m ? a1_3 : a0_3;
      const i32x4& v4 = m ? a1_4 : a0_4;
      const i32x4& v5 = m ? a1_5 : a0_5;
      const i32x4& v6 = m ? a1_6 : a0_6;
      o[pxl]      = 1e-4f * (float)v0[j] + asf0 + bc;
      o[16 + pxl] = 1e-4f * (float)v1[j] + asf1 + bc;
      o[32 + pxl] = 1e-4f * (float)v2[j] + asf2 + bc;
      o[48 + pxl] = 1e-4f * (float)v3[j] + asf3 + bc;
      o[64 + pxl] = 1e-4f * (float)v4[j] + asf4 + bc;
      o[80 + pxl] = 1e-4f * (float)v5[j] + asf5 + bc;
      if (j6 < 108)
        o[j6] = 1e-4f * (float)v6[j] + asf6 + bc;
    }
  }
}

// ---------------- fallback (tiny ws): naive direct conv
__global__ void conv_naive(const int* __restrict__ in, const int* __restrict__ w,
                           const float* __restrict__ bias, float* __restrict__ out) {
  size_t idx = (size_t)blockIdx.x * 256 + threadIdx.x;
  size_t total = (size_t)N_B * C_OUT * H_OUT * W_OUT;
  if (idx >= total) return;
  int x = idx % W_OUT; size_t t = idx / W_OUT;
  int y = t % H_OUT; t /= H_OUT;
  int co = t % C_OUT; int n = (int)(t / C_OUT);
  int acc = 0;
  for (int ci = 0; ci < C_IN; ++ci) {
    const int* ib = in + (((size_t)n * C_IN + ci) * H_IN + y) * W_IN + x;
    const int* wb = w + (((size_t)co * C_IN + ci) * 3) * 3;
    for (int kh = 0; kh < 3; ++kh)
      for (int kw = 0; kw < 3; ++kw)
        acc += (ib[kh * W_IN + kw] - 7) * (wb[kh * 3 + kw] - 3);
  }
  float r = rintf(bias[co] / 0.0001f);
  r = fminf(fmaxf(r, -2147483648.0f), 2147483647.0f);
  out[idx] = (float)acc * (0.01f * 0.01f) + r * 0.0001f;
}

extern "C" void kernel_launch(void* const* d_in, const int* in_sizes, int n_in,
                              void* d_out, int out_size, void* d_ws, size_t ws_size,
                              hipStream_t stream) {
  const int*   in   = (const int*)d_in[0];
  const int*   w    = (const int*)d_in[1];
  const float* bias = (const float*)d_in[2];
  float*       out  = (float*)d_out;

  const size_t WQ_OFF = 0;                          // 294912
  const size_t IP_OFF = 294912;                     // 32*56*8192 = 14680064
  const size_t RS_OFF = IP_OFF + 14680064;          // 401408
  const size_t BC_OFF = RS_OFF + 401408;            // 1024
  const size_t NEED   = BC_OFF + 1024;              // ~15.4 MB

  if (ws_size >= NEED) {
    char* ws = (char*)d_ws;
    signed char* wq3  = (signed char*)(ws + WQ_OFF);
    signed char* ip2  = (signed char*)(ws + IP_OFF);
    int*         rs   = (int*)(ws + RS_OFF);
    float*       bc   = (float*)(ws + BC_OFF);

    prep<<<1920, 256, 0, stream>>>(in, w, bias, ip2, rs, wq3, bc);
    conv_mfma<<<1728, 256, 0, stream>>>(ip2, wq3, rs, bc, out);
  } else {
    size_t total = (size_t)N_B * C_OUT * H_OUT * W_OUT;
    conv_naive<<<(total + 255) / 256, 256, 0, stream>>>(in, w, bias, out);
  }
}